// Round 5
// baseline (155.748 us; speedup 1.0000x reference)
//
#include <hip/hip_runtime.h>
#include <hip/hip_bf16.h>
#include <stdint.h>

#define N_ELx 768
#define EMBx 128
#define TPSx 64
#define EDGE_INx 32
#define EPB 128
#define NBINS 2304   // 3 types * 768 receivers
#define NB_SORT 96
#define MAXSEG 96

typedef __attribute__((ext_vector_type(8))) short bf16x8;
typedef __attribute__((ext_vector_type(4))) float f32x4;

__device__ __forceinline__ short f2bf(float f) {
    union { float f; uint32_t u; } v; v.f = f;
    uint32_t u = v.u;
    uint32_t r = (u + 0x7FFFu + ((u >> 16) & 1u)) >> 16;
    return (short)r;
}

__device__ __forceinline__ float silu_f(float x) {
    return x / (1.0f + __expf(-x));
}

// ---------------- prep kernel: hx tables (MFMA) + B-fragment packing ---------
__global__ __launch_bounds__(256)
void prep_kernel(const float* __restrict__ elec, const float* __restrict__ nuclei,
                 const float* __restrict__ uW, const float* __restrict__ wW,
                 const float* __restrict__ hWee, const float* __restrict__ hbee,
                 const float* __restrict__ hWne, const float* __restrict__ hbne,
                 float* __restrict__ hx0, float* __restrict__ hx1, float* __restrict__ hxn,
                 short* __restrict__ uWfrag, short* __restrict__ wWfrag)
{
    __shared__ __align__(16) short lds_a[16 * 128 * 8];   // 32KB: [kk*4+kc][row][8]
    int b = blockIdx.x;
    int tid = threadIdx.x;
    if (b < 12) {
        // hx0/hx1 = silu(E @ hWee[t] + hbee[t]) via MFMA; 128 rows x 64 cols/block
        int t = b / 6, rb = b % 6;
        const float* W = hWee + t * (128 * 64);
        // stage elec rows rb*128..+127 as bf16 A-chunks
        {
            int row = tid >> 1, half = tid & 1;
            const float4* src = (const float4*)(elec + (size_t)(rb * 128 + row) * 128 + half * 64);
            #pragma unroll
            for (int c = 0; c < 8; ++c) {
                float4 fa = src[c * 2 + 0], fb = src[c * 2 + 1];
                bf16x8 v;
                v[0] = f2bf(fa.x); v[1] = f2bf(fa.y); v[2] = f2bf(fa.z); v[3] = f2bf(fa.w);
                v[4] = f2bf(fb.x); v[5] = f2bf(fb.y); v[6] = f2bf(fb.z); v[7] = f2bf(fb.w);
                int kk = half * 2 + (c >> 2), kc = c & 3;
                *(bf16x8*)&lds_a[((kk * 4 + kc) * 128 + row) * 8] = v;
            }
        }
        __syncthreads();
        int lane = tid & 63, w = tid >> 6, kc = lane >> 4, cr = lane & 15;
        int col = w * 16 + cr;
        bf16x8 bfrag[4];
        #pragma unroll
        for (int kk = 0; kk < 4; ++kk) {
            bf16x8 v;
            #pragma unroll
            for (int j = 0; j < 8; ++j)
                v[j] = f2bf(W[(kk * 32 + kc * 8 + j) * 64 + col]);
            bfrag[kk] = v;
        }
        float bias = hbee[t * 64 + col];
        float* dst = (t == 0 ? hx0 : hx1);
        f32x4 zero4 = {0.f, 0.f, 0.f, 0.f};
        #pragma unroll
        for (int rt = 0; rt < 8; ++rt) {
            f32x4 acc = zero4;
            #pragma unroll
            for (int kk = 0; kk < 4; ++kk) {
                bf16x8 a = *(const bf16x8*)&lds_a[((kk * 4 + kc) * 128 + rt * 16 + cr) * 8];
                acc = __builtin_amdgcn_mfma_f32_16x16x32_bf16(a, bfrag[kk], acc, 0, 0, 0);
            }
            #pragma unroll
            for (int r = 0; r < 4; ++r) {
                int row = rb * 128 + rt * 16 + kc * 4 + r;
                dst[row * 64 + col] = silu_f(acc[r] + bias);
            }
        }
    } else if (b == 12) {
        // hxn: silu(nuclei @ hWne + hbne), 32x64 @ 64x64 (tiny, scalar)
        int lr = tid >> 6, col = tid & 63;
        for (int i = 0; i < 8; ++i) {
            int row = lr * 8 + i;
            float acc = 0.f;
            for (int k = 0; k < 64; ++k)
                acc += nuclei[row * 64 + k] * hWne[k * 64 + col];
            hxn[row * 64 + col] = silu_f(acc + hbne[col]);
        }
    } else {
        // MFMA B-fragment packing (16x16x32: lane l holds B[k][col],
        // col = ct*16 + (l&15), k = (l>>4)*8 + j)
        for (int idx = tid; idx < 3 * 4 * 64; idx += 256) {
            int lane = idx & 63, ct = (idx >> 6) & 3, ty = idx >> 8;
            for (int j = 0; j < 8; ++j) {
                int k = (lane >> 4) * 8 + j, col = ct * 16 + (lane & 15);
                uWfrag[idx * 8 + j] = f2bf(uW[(ty * 32 + k) * 64 + col]);
            }
        }
        for (int idx = tid; idx < 3 * 2 * 4 * 64; idx += 256) {
            int lane = idx & 63, ct = (idx >> 6) & 3, ks = (idx >> 8) & 1, ty = idx >> 9;
            for (int j = 0; j < 8; ++j) {
                int k = ks * 32 + (lane >> 4) * 8 + j, col = ct * 16 + (lane & 15);
                wWfrag[idx * 8 + j] = f2bf(wW[(ty * 64 + k) * 64 + col]);
            }
        }
    }
}

// ---------------- sort: contention-free counting sort by (type, receiver) ----
__device__ __forceinline__ void decode_edge(int i, int n0, int n1,
                                            const int* __restrict__ r0,
                                            const int* __restrict__ r1,
                                            const int* __restrict__ r2,
                                            int& j, int& bin)
{
    int t;
    if (i < n0)            { t = 0; j = i; }
    else if (i < n0 + n1)  { t = 1; j = i - n0; }
    else                   { t = 2; j = i - n0 - n1; }
    int rv = (t == 0 ? r0 : (t == 1 ? r1 : r2))[j];
    bin = t * 768 + rv;
}

__global__ __launch_bounds__(256)
void blockhist_kernel(const int* __restrict__ r0, const int* __restrict__ r1,
                      const int* __restrict__ r2,
                      int n0, int n1, int n2, int* __restrict__ blockHist,
                      float* __restrict__ z)
{
    __shared__ int h[NBINS];
    int tid = threadIdx.x, b = blockIdx.x;
    // fold in z zeroing (replaces a memset launch)
    for (int i = b * 256 + tid; i < 3 * N_ELx * TPSx; i += NB_SORT * 256)
        z[i] = 0.f;
    for (int i = tid; i < NBINS; i += 256) h[i] = 0;
    __syncthreads();
    int total = n0 + n1 + n2;
    int chunk = (total + NB_SORT - 1) / NB_SORT;
    int start = b * chunk, end = min(start + chunk, total);
    for (int i = start + tid; i < end; i += 256) {
        int j, bin;
        decode_edge(i, n0, n1, r0, r1, r2, j, bin);
        atomicAdd(&h[bin], 1);
    }
    __syncthreads();
    for (int i = tid; i < NBINS; i += 256)
        blockHist[i * NB_SORT + b] = h[i];
}

__global__ __launch_bounds__(256)
void binscan_kernel(int* __restrict__ blockHist, int* __restrict__ binTotal)
{
    int bin = blockIdx.x * 256 + threadIdx.x;   // 9 blocks x 256 = 2304
    int* p = blockHist + bin * NB_SORT;
    int run = 0;
    for (int b = 0; b < NB_SORT; ++b) { int v = p[b]; p[b] = run; run += v; }
    binTotal[bin] = run;
}

__global__ __launch_bounds__(256)
void scan_kernel(const int* __restrict__ bins, int* __restrict__ cursor)
{
    __shared__ int part[256];
    int tid = threadIdx.x;
    int l[9]; int s = 0;
    #pragma unroll
    for (int j = 0; j < 9; ++j) { l[j] = bins[tid * 9 + j]; s += l[j]; }
    part[tid] = s;
    __syncthreads();
    for (int off = 1; off < 256; off <<= 1) {
        int v = (tid >= off) ? part[tid - off] : 0;
        __syncthreads();
        part[tid] += v;
        __syncthreads();
    }
    int run = (tid == 0) ? 0 : part[tid - 1];
    #pragma unroll
    for (int j = 0; j < 9; ++j) { cursor[tid * 9 + j] = run; run += l[j]; }
}

__global__ __launch_bounds__(256)
void scatter2_kernel(const int* __restrict__ r0, const int* __restrict__ r1,
                     const int* __restrict__ r2,
                     int n0, int n1, int n2,
                     const int* __restrict__ blockHist,
                     const int* __restrict__ binStart,
                     int* __restrict__ perm)
{
    __shared__ int cursor[NBINS];
    int tid = threadIdx.x, b = blockIdx.x;
    for (int i = tid; i < NBINS; i += 256)
        cursor[i] = binStart[i] + blockHist[i * NB_SORT + b];
    __syncthreads();
    int total = n0 + n1 + n2;
    int chunk = (total + NB_SORT - 1) / NB_SORT;
    int start = b * chunk, end = min(start + chunk, total);
    for (int i = start + tid; i < end; i += 256) {
        int j, bin;
        decode_edge(i, n0, n1, r0, r1, r2, j, bin);
        int pos = atomicAdd(&cursor[bin], 1);   // LDS atomic — fast
        perm[pos] = j;
    }
}

// ---------------- edge kernel: receiver-sorted, segment-aggregated scatter ----
__global__ __launch_bounds__(256)
void edge_kernel(const float* __restrict__ feat0, const float* __restrict__ feat1,
                 const float* __restrict__ feat2,
                 const int* __restrict__ s0, const int* __restrict__ s1, const int* __restrict__ s2,
                 const int* __restrict__ r0, const int* __restrict__ r1, const int* __restrict__ r2,
                 const float* __restrict__ u_b, const float* __restrict__ w_b,
                 const float* __restrict__ hx0, const float* __restrict__ hx1,
                 const float* __restrict__ hxn,
                 const short* __restrict__ uWfrag, const short* __restrict__ wWfrag,
                 const int* __restrict__ perm,
                 float* __restrict__ z,
                 int n0, int n1, int n2, int nb0, int nb1)
{
    // LDS: zloc[96][64] f32 (24KB) overlays a1 (8KB @0) + e (16KB @8KB)
    __shared__ __align__(16) char smem[24576 + 2048];
    short* lds_a1 = (short*)smem;              // [4][128][8] bf16
    short* lds_e  = (short*)(smem + 8192);     // [8][128][8] bf16
    float* zloc   = (float*)smem;              // [MAXSEG][64] f32 (after GEMM2)
    int* sidx    = (int*)(smem + 24576);
    int* ridx    = sidx + 128;
    int* lsid    = ridx + 128;
    int* segRecv = lsid + 128;                 // MAXSEG entries
    int* nsegp   = segRecv + MAXSEG;

    int b = blockIdx.x;
    int t; const float* feat; const int* sn; const int* rc; const float* hx; int nE;
    if (b < nb0)            { t = 0; feat = feat0; sn = s0; rc = r0; hx = hx0; nE = n0; }
    else if (b < nb0 + nb1) { t = 1; b -= nb0; feat = feat1; sn = s1; rc = r1; hx = hx1; nE = n1; }
    else                    { t = 2; b -= nb0 + nb1; feat = feat2; sn = s2; rc = r2; hx = hxn; nE = n2; }
    int e0 = b * EPB;
    int t_off = (t == 0) ? 0 : (t == 1 ? n0 : n0 + n1);
    float* zt = z + t * (N_ELx * TPSx);

    int tid = threadIdx.x;
    // stage feat -> LDS (bf16, MFMA-A chunk layout), via receiver-sorted perm
    {
        int row = tid >> 1, half = tid & 1;
        bool ok = (e0 + row) < nE;
        int pe = ok ? perm[t_off + e0 + row] : 0;
        if (half == 0) sidx[row] = sn[pe];
        else           ridx[row] = ok ? rc[pe] : 0;
        const float4* src = (const float4*)(feat + (size_t)pe * EDGE_INx + half * 16);
        #pragma unroll
        for (int c = 0; c < 2; ++c) {
            float4 fa, fb;
            if (ok) { fa = src[c * 2 + 0]; fb = src[c * 2 + 1]; }
            else    { fa = make_float4(0,0,0,0); fb = make_float4(0,0,0,0); }
            bf16x8 v;
            v[0] = f2bf(fa.x); v[1] = f2bf(fa.y); v[2] = f2bf(fa.z); v[3] = f2bf(fa.w);
            v[4] = f2bf(fb.x); v[5] = f2bf(fb.y); v[6] = f2bf(fb.z); v[7] = f2bf(fb.w);
            int kc = half * 2 + c;
            *(bf16x8*)&lds_a1[(kc * EPB + row) * 8] = v;
        }
    }
    __syncthreads();

    int lane = tid & 63;
    int w = tid >> 6;          // wave id = output col-tile
    int kc = lane >> 4;        // 0..3
    int cr = lane & 15;
    int col = w * 16 + cr;

    // wave 0: segment ids via ballot over sorted receivers (others go to GEMM1)
    // lsid[row] = (# segment starts at rows <= row) - 1
    //           = popc(starts strictly below) - (is_start ? 0 : 1)
    if (tid < 64) {
        int l = tid;
        bool b0 = (l == 0) || (ridx[l] != ridx[l - 1]);
        bool b1 = (ridx[64 + l] != ridx[63 + l]);
        unsigned long long m0 = __ballot(b0), m1 = __ballot(b1);
        unsigned long long lt = (1ull << l) - 1;   // lanes strictly below l
        int id0 = __popcll(m0 & lt) - (b0 ? 0 : 1);
        int id1 = __popcll(m0) + __popcll(m1 & lt) - (b1 ? 0 : 1);
        lsid[l] = id0;
        lsid[64 + l] = id1;
        if (b0 && id0 < MAXSEG) segRecv[id0] = ridx[l];
        if (b1 && id1 < MAXSEG) segRecv[id1] = ridx[64 + l];
        if (l == 0) *nsegp = __popcll(m0) + __popcll(m1);
    }

    f32x4 zero4 = {0.f, 0.f, 0.f, 0.f};

    // GEMM1: e[128x64] = feat[128x32] @ uW[32x64]
    bf16x8 bu = *(const bf16x8*)(uWfrag + ((t * 4 + w) * 64 + lane) * 8);
    float ubc = u_b[t * 64 + col];
    f32x4 d1[8];
    #pragma unroll
    for (int rt = 0; rt < 8; ++rt) {
        bf16x8 a = *(const bf16x8*)&lds_a1[(kc * EPB + rt * 16 + cr) * 8];
        d1[rt] = __builtin_amdgcn_mfma_f32_16x16x32_bf16(a, bu, zero4, 0, 0, 0);
    }
    // silu + write e to LDS (A-layout for GEMM2; k-dim of GEMM2 = col of e)
    {
        int ks = col >> 5, c2 = (col >> 3) & 3, j = col & 7;
        short* ebase = &lds_e[((ks * 4 + c2) * EPB) * 8 + j];
        #pragma unroll
        for (int rt = 0; rt < 8; ++rt) {
            #pragma unroll
            for (int r = 0; r < 4; ++r) {
                int row = rt * 16 + kc * 4 + r;
                ebase[row * 8] = f2bf(silu_f(d1[rt][r] + ubc));
            }
        }
    }
    __syncthreads();

    // GEMM2: we[128x64] = e[128x64] @ wW[64x64]
    bf16x8 bw0 = *(const bf16x8*)(wWfrag + (((t * 2 + 0) * 4 + w) * 64 + lane) * 8);
    bf16x8 bw1 = *(const bf16x8*)(wWfrag + (((t * 2 + 1) * 4 + w) * 64 + lane) * 8);
    f32x4 d2[8];
    #pragma unroll
    for (int rt = 0; rt < 8; ++rt) {
        bf16x8 a0 = *(const bf16x8*)&lds_e[((0 + kc) * EPB + rt * 16 + cr) * 8];
        bf16x8 a1 = *(const bf16x8*)&lds_e[((4 + kc) * EPB + rt * 16 + cr) * 8];
        f32x4 acc = __builtin_amdgcn_mfma_f32_16x16x32_bf16(a0, bw0, zero4, 0, 0, 0);
        d2[rt] = __builtin_amdgcn_mfma_f32_16x16x32_bf16(a1, bw1, acc, 0, 0, 0);
    }
    __syncthreads();   // lds_a1/lds_e dead; lsid/nseg visible

    int nSeg = *nsegp;
    float wbc = w_b[t * 64 + col];

    if (nSeg == 1) {
        // fast path: whole block one receiver — pure in-register reduction
        float tot = 0.f;
        #pragma unroll
        for (int rt = 0; rt < 8; ++rt) {
            #pragma unroll
            for (int r = 0; r < 4; ++r) {
                int row = rt * 16 + kc * 4 + r;
                if (e0 + row < nE) {
                    float we = silu_f(d2[rt][r] + wbc);
                    tot += we * hx[sidx[row] * TPSx + col];
                }
            }
        }
        tot += __shfl_xor(tot, 16, 64);
        tot += __shfl_xor(tot, 32, 64);
        if (kc == 0) atomicAdd(&zt[ridx[0] * 64 + col], tot);
    } else {
        int nS = min(nSeg, MAXSEG);
        for (int i = tid; i < nS * 64; i += 256) zloc[i] = 0.f;
        __syncthreads();
        #pragma unroll
        for (int rt = 0; rt < 8; ++rt) {
            int row0 = rt * 16 + kc * 4;
            float m[4];
            #pragma unroll
            for (int r = 0; r < 4; ++r) {
                int row = row0 + r;
                m[r] = 0.f;
                if (e0 + row < nE) {
                    float we = silu_f(d2[rt][r] + wbc);
                    m[r] = we * hx[sidx[row] * TPSx + col];
                }
            }
            int l0 = lsid[row0], l3 = lsid[row0 + 3];
            if (l0 == l3) {
                float s = (m[0] + m[1]) + (m[2] + m[3]);
                if (l0 < MAXSEG) atomicAdd(&zloc[l0 * 64 + col], s);
                else             atomicAdd(&zt[ridx[row0] * 64 + col], s);
            } else {
                #pragma unroll
                for (int r = 0; r < 4; ++r) {
                    int li = lsid[row0 + r];
                    if (li < MAXSEG) atomicAdd(&zloc[li * 64 + col], m[r]);
                    else             atomicAdd(&zt[ridx[row0 + r] * 64 + col], m[r]);
                }
            }
        }
        __syncthreads();
        for (int i = tid; i < nS * 64; i += 256)
            atomicAdd(&zt[segRecv[i >> 6] * 64 + (i & 63)], zloc[i]);
    }
}

// ---------------- final kernel: g-subnets + residual ----------------
__global__ __launch_bounds__(128)
void final_kernel(const float* __restrict__ elec, const float* __restrict__ z,
                  const float* __restrict__ gWres, const float* __restrict__ gbres,
                  const float* __restrict__ gWz, const float* __restrict__ gbz,
                  float* __restrict__ out)
{
    __shared__ float xe[4 * 128];
    __shared__ float xz[3 * 4 * 64];
    int b = blockIdx.x;     // 0..191
    int tid = threadIdx.x;  // 0..127
    int row0 = b * 4;
    for (int i = tid; i < 4 * 128; i += 128)
        xe[i] = elec[row0 * 128 + i];
    for (int i = tid; i < 3 * 4 * 64; i += 128) {
        int t = i >> 8; int rr = (i >> 6) & 3; int k = i & 63;
        xz[i] = z[t * N_ELx * 64 + (row0 + rr) * 64 + k];
    }
    __syncthreads();

    int col = tid;
    float accr[4] = {0.f, 0.f, 0.f, 0.f};
    for (int k = 0; k < 128; ++k) {
        float wv = gWres[k * 128 + col];
        #pragma unroll
        for (int r = 0; r < 4; ++r) accr[r] += xe[r * 128 + k] * wv;
    }
    float o[4];
    float br = gbres[col];
    #pragma unroll
    for (int r = 0; r < 4; ++r) o[r] = silu_f(accr[r] + br) + xe[r * 128 + col];

    for (int t = 0; t < 3; ++t) {
        float accz[4] = {0.f, 0.f, 0.f, 0.f};
        for (int k = 0; k < 64; ++k) {
            float wv = gWz[(t * 64 + k) * 128 + col];
            #pragma unroll
            for (int r = 0; r < 4; ++r) accz[r] += xz[t * 256 + r * 64 + k] * wv;
        }
        float bz = gbz[t * 128 + col];
        #pragma unroll
        for (int r = 0; r < 4; ++r) o[r] += silu_f(accz[r] + bz);
    }
    #pragma unroll
    for (int r = 0; r < 4; ++r) out[(row0 + r) * 128 + col] = o[r];
}

extern "C" void kernel_launch(void* const* d_in, const int* in_sizes, int n_in,
                              void* d_out, int out_size, void* d_ws, size_t ws_size,
                              hipStream_t stream)
{
    const float* elec   = (const float*)d_in[0];
    const float* nuclei = (const float*)d_in[1];
    const float* feat0  = (const float*)d_in[2];
    const float* feat1  = (const float*)d_in[3];
    const float* feat2  = (const float*)d_in[4];
    const int*   s0     = (const int*)d_in[5];
    const int*   r0     = (const int*)d_in[6];
    const int*   s1     = (const int*)d_in[7];
    const int*   r1     = (const int*)d_in[8];
    const int*   s2     = (const int*)d_in[9];
    const int*   r2     = (const int*)d_in[10];
    const float* u_W    = (const float*)d_in[11];
    const float* u_b    = (const float*)d_in[12];
    const float* w_W    = (const float*)d_in[13];
    const float* w_b    = (const float*)d_in[14];
    const float* hWee   = (const float*)d_in[15];
    const float* hbee   = (const float*)d_in[16];
    const float* hWne   = (const float*)d_in[17];
    const float* hbne   = (const float*)d_in[18];
    const float* gWres  = (const float*)d_in[19];
    const float* gbres  = (const float*)d_in[20];
    const float* gWz    = (const float*)d_in[21];
    const float* gbz    = (const float*)d_in[22];
    float* out = (float*)d_out;

    char* ws = (char*)d_ws;
    float* hx0      = (float*)(ws + 0);           // 196608
    float* hx1      = (float*)(ws + 196608);      // 196608
    float* hxn      = (float*)(ws + 393216);      // 8192
    float* z        = (float*)(ws + 401408);      // 589824
    short* uWfrag   = (short*)(ws + 991232);      // 12288
    short* wWfrag   = (short*)(ws + 1003520);     // 24576
    int*   binTotal = (int*)(ws + 1028096);       // 9216
    int*   binStart = (int*)(ws + 1037312);       // 9216
    int*   perm     = (int*)(ws + 1046528);       // 2454528
    int*   blockHist= (int*)(ws + 3501056);       // 884736  (end: 4385792)

    int n0 = in_sizes[2] / EDGE_INx;
    int n1 = in_sizes[3] / EDGE_INx;
    int n2 = in_sizes[4] / EDGE_INx;
    int nb0 = (n0 + EPB - 1) / EPB;
    int nb1 = (n1 + EPB - 1) / EPB;
    int nb2 = (n2 + EPB - 1) / EPB;

    prep_kernel<<<14, 256, 0, stream>>>(elec, nuclei, u_W, w_W, hWee, hbee,
                                        hWne, hbne, hx0, hx1, hxn, uWfrag, wWfrag);
    blockhist_kernel<<<NB_SORT, 256, 0, stream>>>(r0, r1, r2, n0, n1, n2, blockHist, z);
    binscan_kernel<<<NBINS / 256, 256, 0, stream>>>(blockHist, binTotal);
    scan_kernel<<<1, 256, 0, stream>>>(binTotal, binStart);
    scatter2_kernel<<<NB_SORT, 256, 0, stream>>>(r0, r1, r2, n0, n1, n2,
                                                 blockHist, binStart, perm);
    edge_kernel<<<nb0 + nb1 + nb2, 256, 0, stream>>>(
        feat0, feat1, feat2, s0, s1, s2, r0, r1, r2,
        u_b, w_b, hx0, hx1, hxn, uWfrag, wWfrag, perm, z,
        n0, n1, n2, nb0, nb1);
    final_kernel<<<192, 128, 0, stream>>>(elec, z, gWres, gbres, gWz, gbz, out);
}

// Round 6
// 133.117 us; speedup vs baseline: 1.1700x; 1.1700x over previous
//
#include <hip/hip_runtime.h>
#include <hip/hip_bf16.h>
#include <stdint.h>

#define N_ELx 768
#define EMBx 128
#define TPSx 64
#define EDGE_INx 32
#define EPB 128
#define NBINS 2304   // 3 types * 768 receivers
#define NB_SORT 96

typedef __attribute__((ext_vector_type(8))) short bf16x8;
typedef __attribute__((ext_vector_type(4))) float f32x4;
typedef __attribute__((ext_vector_type(4))) uint32_t u32x4;

__device__ __forceinline__ short f2bf(float f) {
    union { float f; uint32_t u; } v; v.f = f;
    uint32_t u = v.u;
    uint32_t r = (u + 0x7FFFu + ((u >> 16) & 1u)) >> 16;
    return (short)r;
}

// pack 2 floats -> 2 bf16 in one u32 (a = low/element0, b = high/element1),
// round-half-up via +0x8000 then byte-perm (1 v_perm + 2 v_add)
__device__ __forceinline__ uint32_t pk_rnd(float a, float b) {
    uint32_t ua = __float_as_uint(a) + 0x8000u;
    uint32_t ub = __float_as_uint(b) + 0x8000u;
    return __builtin_amdgcn_perm(ub, ua, 0x07060302);
}

__device__ __forceinline__ bf16x8 mk8(uint32_t a, uint32_t b, uint32_t c, uint32_t d) {
    union { u32x4 u; bf16x8 h; } x;
    x.u = (u32x4){a, b, c, d};
    return x.h;
}

__device__ __forceinline__ float silu_f(float x) {
    return x / (1.0f + __expf(-x));
}

// ---------------- prep kernel: hx tables (MFMA) + fragment packing ----------
__global__ __launch_bounds__(256)
void prep_kernel(const float* __restrict__ elec, const float* __restrict__ nuclei,
                 const float* __restrict__ uW, const float* __restrict__ wW,
                 const float* __restrict__ hWee, const float* __restrict__ hbee,
                 const float* __restrict__ hWne, const float* __restrict__ hbne,
                 float* __restrict__ hx0, float* __restrict__ hx1, float* __restrict__ hxn,
                 short* __restrict__ ufragT, short* __restrict__ wWfrag)
{
    __shared__ __align__(16) short lds_a[16 * 128 * 8];   // 32KB: [kk*4+kc][row][8]
    int b = blockIdx.x;
    int tid = threadIdx.x;
    if (b < 12) {
        // hx0/hx1 = silu(E @ hWee[t] + hbee[t]) via MFMA; 128 rows x 64 cols/block
        int t = b / 6, rb = b % 6;
        const float* W = hWee + t * (128 * 64);
        {
            int row = tid >> 1, half = tid & 1;
            const float4* src = (const float4*)(elec + (size_t)(rb * 128 + row) * 128 + half * 64);
            #pragma unroll
            for (int c = 0; c < 8; ++c) {
                float4 fa = src[c * 2 + 0], fb = src[c * 2 + 1];
                bf16x8 v;
                v[0] = f2bf(fa.x); v[1] = f2bf(fa.y); v[2] = f2bf(fa.z); v[3] = f2bf(fa.w);
                v[4] = f2bf(fb.x); v[5] = f2bf(fb.y); v[6] = f2bf(fb.z); v[7] = f2bf(fb.w);
                int kk = half * 2 + (c >> 2), kc = c & 3;
                *(bf16x8*)&lds_a[((kk * 4 + kc) * 128 + row) * 8] = v;
            }
        }
        __syncthreads();
        int lane = tid & 63, w = tid >> 6, kc = lane >> 4, cr = lane & 15;
        int col = w * 16 + cr;
        bf16x8 bfrag[4];
        #pragma unroll
        for (int kk = 0; kk < 4; ++kk) {
            bf16x8 v;
            #pragma unroll
            for (int j = 0; j < 8; ++j)
                v[j] = f2bf(W[(kk * 32 + kc * 8 + j) * 64 + col]);
            bfrag[kk] = v;
        }
        float bias = hbee[t * 64 + col];
        float* dst = (t == 0 ? hx0 : hx1);
        f32x4 zero4 = {0.f, 0.f, 0.f, 0.f};
        #pragma unroll
        for (int rt = 0; rt < 8; ++rt) {
            f32x4 acc = zero4;
            #pragma unroll
            for (int kk = 0; kk < 4; ++kk) {
                bf16x8 a = *(const bf16x8*)&lds_a[((kk * 4 + kc) * 128 + rt * 16 + cr) * 8];
                acc = __builtin_amdgcn_mfma_f32_16x16x32_bf16(a, bfrag[kk], acc, 0, 0, 0);
            }
            #pragma unroll
            for (int r = 0; r < 4; ++r) {
                int row = rb * 128 + rt * 16 + kc * 4 + r;
                dst[row * 64 + col] = silu_f(acc[r] + bias);
            }
        }
    } else if (b == 12) {
        // hxn: silu(nuclei @ hWne + hbne), 32x64 @ 64x64 (tiny, scalar)
        int lr = tid >> 6, col = tid & 63;
        for (int i = 0; i < 8; ++i) {
            int row = lr * 8 + i;
            float acc = 0.f;
            for (int k = 0; k < 64; ++k)
                acc += nuclei[row * 64 + k] * hWne[k * 64 + col];
            hxn[row * 64 + col] = silu_f(acc + hbne[col]);
        }
    } else {
        // ufragT: A-fragment of uW^T. Lane(lg,cr), tile tr:
        //   A[row = ucol = tr*16+cr][k = featcol = lg*8+j] = uW[featcol][ucol]
        for (int idx = tid; idx < 3 * 4 * 64; idx += 256) {
            int lane = idx & 63, tr = (idx >> 6) & 3, ty = idx >> 8;
            int lg = lane >> 4, cr = lane & 15;
            for (int j = 0; j < 8; ++j)
                ufragT[idx * 8 + j] =
                    f2bf(uW[(ty * EDGE_INx + lg * 8 + j) * TPSx + tr * 16 + cr]);
        }
        // wWfrag: B-fragment of wW (unchanged, verified):
        //   B[k = ucol = ks*32+lg*8+j][col = wcol = tn*16+cr]
        for (int idx = tid; idx < 3 * 2 * 4 * 64; idx += 256) {
            int lane = idx & 63, ct = (idx >> 6) & 3, ks = (idx >> 8) & 1, ty = idx >> 9;
            for (int j = 0; j < 8; ++j) {
                int k = ks * 32 + (lane >> 4) * 8 + j, col = ct * 16 + (lane & 15);
                wWfrag[idx * 8 + j] = f2bf(wW[(ty * 64 + k) * 64 + col]);
            }
        }
    }
}

// ---------------- sort: contention-free counting sort by (type, receiver) ----
__device__ __forceinline__ void decode_edge(int i, int n0, int n1,
                                            const int* __restrict__ r0,
                                            const int* __restrict__ r1,
                                            const int* __restrict__ r2,
                                            int& j, int& bin)
{
    int t;
    if (i < n0)            { t = 0; j = i; }
    else if (i < n0 + n1)  { t = 1; j = i - n0; }
    else                   { t = 2; j = i - n0 - n1; }
    int rv = (t == 0 ? r0 : (t == 1 ? r1 : r2))[j];
    bin = t * 768 + rv;
}

__global__ __launch_bounds__(256)
void blockhist_kernel(const int* __restrict__ r0, const int* __restrict__ r1,
                      const int* __restrict__ r2,
                      int n0, int n1, int n2, int* __restrict__ blockHist,
                      float* __restrict__ z)
{
    __shared__ int h[NBINS];
    int tid = threadIdx.x, b = blockIdx.x;
    for (int i = b * 256 + tid; i < 3 * N_ELx * TPSx; i += NB_SORT * 256)
        z[i] = 0.f;
    for (int i = tid; i < NBINS; i += 256) h[i] = 0;
    __syncthreads();
    int total = n0 + n1 + n2;
    int chunk = (total + NB_SORT - 1) / NB_SORT;
    int start = b * chunk, end = min(start + chunk, total);
    for (int i = start + tid; i < end; i += 256) {
        int j, bin;
        decode_edge(i, n0, n1, r0, r1, r2, j, bin);
        atomicAdd(&h[bin], 1);
    }
    __syncthreads();
    for (int i = tid; i < NBINS; i += 256)
        blockHist[i * NB_SORT + b] = h[i];
}

__global__ __launch_bounds__(256)
void binscan_kernel(int* __restrict__ blockHist, int* __restrict__ binTotal)
{
    int bin = blockIdx.x * 256 + threadIdx.x;
    int* p = blockHist + bin * NB_SORT;
    int run = 0;
    for (int b = 0; b < NB_SORT; ++b) { int v = p[b]; p[b] = run; run += v; }
    binTotal[bin] = run;
}

__global__ __launch_bounds__(256)
void scan_kernel(const int* __restrict__ bins, int* __restrict__ cursor)
{
    __shared__ int part[256];
    int tid = threadIdx.x;
    int l[9]; int s = 0;
    #pragma unroll
    for (int j = 0; j < 9; ++j) { l[j] = bins[tid * 9 + j]; s += l[j]; }
    part[tid] = s;
    __syncthreads();
    for (int off = 1; off < 256; off <<= 1) {
        int v = (tid >= off) ? part[tid - off] : 0;
        __syncthreads();
        part[tid] += v;
        __syncthreads();
    }
    int run = (tid == 0) ? 0 : part[tid - 1];
    #pragma unroll
    for (int j = 0; j < 9; ++j) { cursor[tid * 9 + j] = run; run += l[j]; }
}

__global__ __launch_bounds__(256)
void scatter2_kernel(const int* __restrict__ r0, const int* __restrict__ r1,
                     const int* __restrict__ r2,
                     int n0, int n1, int n2,
                     const int* __restrict__ blockHist,
                     const int* __restrict__ binStart,
                     int* __restrict__ perm)
{
    __shared__ int cursor[NBINS];
    int tid = threadIdx.x, b = blockIdx.x;
    for (int i = tid; i < NBINS; i += 256)
        cursor[i] = binStart[i] + blockHist[i * NB_SORT + b];
    __syncthreads();
    int total = n0 + n1 + n2;
    int chunk = (total + NB_SORT - 1) / NB_SORT;
    int start = b * chunk, end = min(start + chunk, total);
    for (int i = start + tid; i < end; i += 256) {
        int j, bin;
        decode_edge(i, n0, n1, r0, r1, r2, j, bin);
        int pos = atomicAdd(&cursor[bin], 1);
        perm[pos] = j;
    }
}

// ---------------- edge kernel: barrier-free register-only pipeline ----------
// GEMM1 (swapped): e^T = mfma(A = uW^T frag, B = feat^T loaded from global)
//   -> lane holds e^T[ucol = tr*16+lg*4+r][edge = base+tc*16+cr]
// redistribute (16 shfl + 8 sel per tile) -> A-frag of e
// GEMM2 (normal): we = mfma(A = e frag, B = wWfrag)
//   -> lane holds we[edge = base+tc*16+lg*4+r][wcol = tn*16+cr]  (edges reg-local!)
// epilogue: silu * hx[sender], segment reduce over r (regs) + lg (2 shfl_xor)
__global__ __launch_bounds__(256)
void edge_kernel(const float* __restrict__ feat0, const float* __restrict__ feat1,
                 const float* __restrict__ feat2,
                 const int* __restrict__ s0, const int* __restrict__ s1, const int* __restrict__ s2,
                 const int* __restrict__ r0, const int* __restrict__ r1, const int* __restrict__ r2,
                 const float* __restrict__ u_b, const float* __restrict__ w_b,
                 const float* __restrict__ hx0, const float* __restrict__ hx1,
                 const float* __restrict__ hxn,
                 const short* __restrict__ ufragT, const short* __restrict__ wWfrag,
                 const int* __restrict__ perm,
                 float* __restrict__ z,
                 int n0, int n1, int n2, int nb0, int nb1)
{
    int b = blockIdx.x;
    int t; const float* feat; const int* sn; const int* rc; const float* hx; int nE;
    if (b < nb0)            { t = 0; feat = feat0; sn = s0; rc = r0; hx = hx0; nE = n0; }
    else if (b < nb0 + nb1) { t = 1; b -= nb0; feat = feat1; sn = s1; rc = r1; hx = hx1; nE = n1; }
    else                    { t = 2; b -= nb0 + nb1; feat = feat2; sn = s2; rc = r2; hx = hxn; nE = n2; }

    int tid = threadIdx.x;
    int w = tid >> 6, lane = tid & 63, lg = lane >> 4, cr = lane & 15;
    int ebase = b * EPB + w * 32;
    int t_off = (t == 0) ? 0 : (t == 1 ? n0 : n0 + n1);
    float* zt = z + t * (N_ELx * TPSx);

    // weight fragments + biases (L1-hot broadcast loads)
    bf16x8 uf[4];
    #pragma unroll
    for (int tr = 0; tr < 4; ++tr)
        uf[tr] = *(const bf16x8*)(ufragT + ((t * 4 + tr) * 64 + lane) * 8);
    bf16x8 wf[4][2];
    #pragma unroll
    for (int tn = 0; tn < 4; ++tn)
        #pragma unroll
        for (int ks = 0; ks < 2; ++ks)
            wf[tn][ks] = *(const bf16x8*)(wWfrag + (((t * 2 + ks) * 4 + tn) * 64 + lane) * 8);
    float4 ubv[4];
    #pragma unroll
    for (int tr = 0; tr < 4; ++tr)
        ubv[tr] = *(const float4*)(u_b + t * 64 + tr * 16 + lg * 4);
    float wbv[4];
    #pragma unroll
    for (int tn = 0; tn < 4; ++tn)
        wbv[tn] = w_b[t * 64 + tn * 16 + cr];

    const int srcA = ((lg & 1) * 2) * 16 + cr;   // lane-group 2*(lg&1), same cr
    const int srcB = srcA + 16;
    const bool selLow = (lg < 2);                // tr' = 2ks + (lg>>1)
    f32x4 zero4 = {0.f, 0.f, 0.f, 0.f};

    #pragma unroll 1
    for (int tc = 0; tc < 2; ++tc) {
        // ---- edge meta ----
        int pF;
        {
            int p = ebase + tc * 16 + cr;
            pF = perm[t_off + min(p, nE - 1)];
        }
        int sidv[4], ridv[4];
        bool aE[4];
        #pragma unroll
        for (int r = 0; r < 4; ++r) {
            int p = ebase + tc * 16 + lg * 4 + r;
            aE[r] = p < nE;
            int pe = perm[t_off + min(p, nE - 1)];
            sidv[r] = sn[pe];
            ridv[r] = rc[pe];
        }

        // ---- feat B-frag straight from global: feat[edge=cr][featcol=lg*8+j] ----
        const float4* fp = (const float4*)(feat + (size_t)pF * EDGE_INx + lg * 8);
        float4 fa = fp[0], fc = fp[1];
        bf16x8 fB = mk8(pk_rnd(fa.x, fa.y), pk_rnd(fa.z, fa.w),
                        pk_rnd(fc.x, fc.y), pk_rnd(fc.z, fc.w));

        // ---- GEMM1: e^T tiles ----
        f32x4 d1[4];
        #pragma unroll
        for (int tr = 0; tr < 4; ++tr)
            d1[tr] = __builtin_amdgcn_mfma_f32_16x16x32_bf16(uf[tr], fB, zero4, 0, 0, 0);

        // ---- silu + pack pairs ----
        uint32_t pk1[4][2];
        #pragma unroll
        for (int tr = 0; tr < 4; ++tr) {
            float v0 = silu_f(d1[tr][0] + ubv[tr].x);
            float v1 = silu_f(d1[tr][1] + ubv[tr].y);
            float v2 = silu_f(d1[tr][2] + ubv[tr].z);
            float v3 = silu_f(d1[tr][3] + ubv[tr].w);
            pk1[tr][0] = pk_rnd(v0, v1);
            pk1[tr][1] = pk_rnd(v2, v3);
        }

        // ---- redistribute to A-frag of e: lane needs e[edge=cr][ucol=32ks+8lg+j] ----
        bf16x8 ebf[2];
        #pragma unroll
        for (int ks = 0; ks < 2; ++ks) {
            int t0 = 2 * ks, t1 = 2 * ks + 1;
            uint32_t a0 = (uint32_t)__shfl((int)pk1[t0][0], srcA, 64);
            uint32_t b0 = (uint32_t)__shfl((int)pk1[t1][0], srcA, 64);
            uint32_t a1 = (uint32_t)__shfl((int)pk1[t0][1], srcA, 64);
            uint32_t b1 = (uint32_t)__shfl((int)pk1[t1][1], srcA, 64);
            uint32_t a2 = (uint32_t)__shfl((int)pk1[t0][0], srcB, 64);
            uint32_t b2 = (uint32_t)__shfl((int)pk1[t1][0], srcB, 64);
            uint32_t a3 = (uint32_t)__shfl((int)pk1[t0][1], srcB, 64);
            uint32_t b3 = (uint32_t)__shfl((int)pk1[t1][1], srcB, 64);
            ebf[ks] = mk8(selLow ? a0 : b0, selLow ? a1 : b1,
                          selLow ? a2 : b2, selLow ? a3 : b3);
        }

        // ---- hx gather (independent of GEMM2 -> overlaps MFMA) ----
        float hv[4][4];   // [tn][r]
        #pragma unroll
        for (int r = 0; r < 4; ++r) {
            const float* hp = hx + sidv[r] * TPSx + cr;
            #pragma unroll
            for (int tn = 0; tn < 4; ++tn)
                hv[tn][r] = aE[r] ? hp[tn * 16] : 0.f;
        }

        // ---- GEMM2: we tiles ----
        f32x4 d2[4];
        #pragma unroll
        for (int tn = 0; tn < 4; ++tn) {
            f32x4 acc = __builtin_amdgcn_mfma_f32_16x16x32_bf16(ebf[0], wf[tn][0], zero4, 0, 0, 0);
            d2[tn] = __builtin_amdgcn_mfma_f32_16x16x32_bf16(ebf[1], wf[tn][1], acc, 0, 0, 0);
        }

        // ---- message values ----
        float m[4][4];   // [tn][r]
        #pragma unroll
        for (int tn = 0; tn < 4; ++tn)
            #pragma unroll
            for (int r = 0; r < 4; ++r)
                m[tn][r] = silu_f(d2[tn][r] + wbv[tn]) * hv[tn][r];

        // ---- segment reduction over the 16 sorted edges of this tile ----
        int rF = __shfl(ridv[0], cr, 64);        // first edge's receiver (lg0)
        int rL = __shfl(ridv[3], 48 + cr, 64);   // last edge's receiver (lg3)
        if (rF == rL) {
            // whole tile one receiver: reg-sum over r, butterfly over lg
            #pragma unroll
            for (int tn = 0; tn < 4; ++tn) {
                float v = (m[tn][0] + m[tn][1]) + (m[tn][2] + m[tn][3]);
                v += __shfl_xor(v, 16, 64);
                v += __shfl_xor(v, 32, 64);
                if (lg == 0) atomicAdd(&zt[rF * 64 + tn * 16 + cr], v);
            }
        } else {
            // rare: per-lane serial flush over its 4 consecutive sorted edges
            float a0 = m[0][0], a1 = m[1][0], a2 = m[2][0], a3 = m[3][0];
            int curR = ridv[0];
            #pragma unroll
            for (int r = 1; r < 4; ++r) {
                if (ridv[r] != curR) {
                    atomicAdd(&zt[curR * 64 +  0 + cr], a0);
                    atomicAdd(&zt[curR * 64 + 16 + cr], a1);
                    atomicAdd(&zt[curR * 64 + 32 + cr], a2);
                    atomicAdd(&zt[curR * 64 + 48 + cr], a3);
                    a0 = m[0][r]; a1 = m[1][r]; a2 = m[2][r]; a3 = m[3][r];
                    curR = ridv[r];
                } else {
                    a0 += m[0][r]; a1 += m[1][r]; a2 += m[2][r]; a3 += m[3][r];
                }
            }
            atomicAdd(&zt[curR * 64 +  0 + cr], a0);
            atomicAdd(&zt[curR * 64 + 16 + cr], a1);
            atomicAdd(&zt[curR * 64 + 32 + cr], a2);
            atomicAdd(&zt[curR * 64 + 48 + cr], a3);
        }
    }
}

// ---------------- final kernel: g-subnets + residual ----------------
__global__ __launch_bounds__(128)
void final_kernel(const float* __restrict__ elec, const float* __restrict__ z,
                  const float* __restrict__ gWres, const float* __restrict__ gbres,
                  const float* __restrict__ gWz, const float* __restrict__ gbz,
                  float* __restrict__ out)
{
    __shared__ float xe[4 * 128];
    __shared__ float xz[3 * 4 * 64];
    int b = blockIdx.x;
    int tid = threadIdx.x;
    int row0 = b * 4;
    for (int i = tid; i < 4 * 128; i += 128)
        xe[i] = elec[row0 * 128 + i];
    for (int i = tid; i < 3 * 4 * 64; i += 128) {
        int t = i >> 8; int rr = (i >> 6) & 3; int k = i & 63;
        xz[i] = z[t * N_ELx * 64 + (row0 + rr) * 64 + k];
    }
    __syncthreads();

    int col = tid;
    float accr[4] = {0.f, 0.f, 0.f, 0.f};
    for (int k = 0; k < 128; ++k) {
        float wv = gWres[k * 128 + col];
        #pragma unroll
        for (int r = 0; r < 4; ++r) accr[r] += xe[r * 128 + k] * wv;
    }
    float o[4];
    float br = gbres[col];
    #pragma unroll
    for (int r = 0; r < 4; ++r) o[r] = silu_f(accr[r] + br) + xe[r * 128 + col];

    for (int t = 0; t < 3; ++t) {
        float accz[4] = {0.f, 0.f, 0.f, 0.f};
        for (int k = 0; k < 64; ++k) {
            float wv = gWz[(t * 64 + k) * 128 + col];
            #pragma unroll
            for (int r = 0; r < 4; ++r) accz[r] += xz[t * 256 + r * 64 + k] * wv;
        }
        float bz = gbz[t * 128 + col];
        #pragma unroll
        for (int r = 0; r < 4; ++r) o[r] += silu_f(accz[r] + bz);
    }
    #pragma unroll
    for (int r = 0; r < 4; ++r) out[(row0 + r) * 128 + col] = o[r];
}

extern "C" void kernel_launch(void* const* d_in, const int* in_sizes, int n_in,
                              void* d_out, int out_size, void* d_ws, size_t ws_size,
                              hipStream_t stream)
{
    const float* elec   = (const float*)d_in[0];
    const float* nuclei = (const float*)d_in[1];
    const float* feat0  = (const float*)d_in[2];
    const float* feat1  = (const float*)d_in[3];
    const float* feat2  = (const float*)d_in[4];
    const int*   s0     = (const int*)d_in[5];
    const int*   r0     = (const int*)d_in[6];
    const int*   s1     = (const int*)d_in[7];
    const int*   r1     = (const int*)d_in[8];
    const int*   s2     = (const int*)d_in[9];
    const int*   r2     = (const int*)d_in[10];
    const float* u_W    = (const float*)d_in[11];
    const float* u_b    = (const float*)d_in[12];
    const float* w_W    = (const float*)d_in[13];
    const float* w_b    = (const float*)d_in[14];
    const float* hWee   = (const float*)d_in[15];
    const float* hbee   = (const float*)d_in[16];
    const float* hWne   = (const float*)d_in[17];
    const float* hbne   = (const float*)d_in[18];
    const float* gWres  = (const float*)d_in[19];
    const float* gbres  = (const float*)d_in[20];
    const float* gWz    = (const float*)d_in[21];
    const float* gbz    = (const float*)d_in[22];
    float* out = (float*)d_out;

    char* ws = (char*)d_ws;
    float* hx0      = (float*)(ws + 0);           // 196608
    float* hx1      = (float*)(ws + 196608);      // 196608
    float* hxn      = (float*)(ws + 393216);      // 8192
    float* z        = (float*)(ws + 401408);      // 589824
    short* ufragT   = (short*)(ws + 991232);      // 12288
    short* wWfrag   = (short*)(ws + 1003520);     // 24576
    int*   binTotal = (int*)(ws + 1028096);       // 9216
    int*   binStart = (int*)(ws + 1037312);       // 9216
    int*   perm     = (int*)(ws + 1046528);       // 2454528
    int*   blockHist= (int*)(ws + 3501056);       // 884736  (end: 4385792)

    int n0 = in_sizes[2] / EDGE_INx;
    int n1 = in_sizes[3] / EDGE_INx;
    int n2 = in_sizes[4] / EDGE_INx;
    int nb0 = (n0 + EPB - 1) / EPB;
    int nb1 = (n1 + EPB - 1) / EPB;
    int nb2 = (n2 + EPB - 1) / EPB;

    prep_kernel<<<14, 256, 0, stream>>>(elec, nuclei, u_W, w_W, hWee, hbee,
                                        hWne, hbne, hx0, hx1, hxn, ufragT, wWfrag);
    blockhist_kernel<<<NB_SORT, 256, 0, stream>>>(r0, r1, r2, n0, n1, n2, blockHist, z);
    binscan_kernel<<<NBINS / 256, 256, 0, stream>>>(blockHist, binTotal);
    scan_kernel<<<1, 256, 0, stream>>>(binTotal, binStart);
    scatter2_kernel<<<NB_SORT, 256, 0, stream>>>(r0, r1, r2, n0, n1, n2,
                                                 blockHist, binStart, perm);
    edge_kernel<<<nb0 + nb1 + nb2, 256, 0, stream>>>(
        feat0, feat1, feat2, s0, s1, s2, r0, r1, r2,
        u_b, w_b, hx0, hx1, hxn, ufragT, wWfrag, perm, z,
        n0, n1, n2, nb0, nb1);
    final_kernel<<<192, 128, 0, stream>>>(elec, z, gWres, gbres, gWz, gbz, out);
}

// Round 7
// 129.902 us; speedup vs baseline: 1.1990x; 1.0248x over previous
//
#include <hip/hip_runtime.h>
#include <hip/hip_bf16.h>
#include <stdint.h>

#define N_ELx 768
#define EMBx 128
#define TPSx 64
#define EDGE_INx 32
#define EPB 512            // edges per block (4 waves x 128)
#define NBINS 2304         // 3 types * 768 receivers
#define NB_SORT 96

typedef __attribute__((ext_vector_type(8))) short bf16x8;
typedef __attribute__((ext_vector_type(4))) float f32x4;
typedef __attribute__((ext_vector_type(4))) uint32_t u32x4;

__device__ __forceinline__ short f2bf(float f) {
    union { float f; uint32_t u; } v; v.f = f;
    uint32_t u = v.u;
    uint32_t r = (u + 0x7FFFu + ((u >> 16) & 1u)) >> 16;
    return (short)r;
}

// pack 2 floats -> 2 bf16 in one u32 (round-half-up: +0x8000 then byte-perm)
__device__ __forceinline__ uint32_t pk_rnd(float a, float b) {
    uint32_t ua = __float_as_uint(a) + 0x8000u;
    uint32_t ub = __float_as_uint(b) + 0x8000u;
    return __builtin_amdgcn_perm(ub, ua, 0x07060302);
}

__device__ __forceinline__ bf16x8 mk8(uint32_t a, uint32_t b, uint32_t c, uint32_t d) {
    union { u32x4 u; bf16x8 h; } x;
    x.u = (u32x4){a, b, c, d};
    return x.h;
}

__device__ __forceinline__ float silu_f(float x) {
    return x / (1.0f + __expf(-x));
}

// ---------------- setup kernel: prep (blocks 0..13) + blockhist (14..109) ----
__global__ __launch_bounds__(256)
void setup_kernel(const float* __restrict__ elec, const float* __restrict__ nuclei,
                  const float* __restrict__ uW, const float* __restrict__ wW,
                  const float* __restrict__ hWee, const float* __restrict__ hbee,
                  const float* __restrict__ hWne, const float* __restrict__ hbne,
                  float* __restrict__ hx0, float* __restrict__ hx1, float* __restrict__ hxn,
                  short* __restrict__ ufragT, short* __restrict__ wWfrag,
                  const int* __restrict__ r0, const int* __restrict__ r1,
                  const int* __restrict__ r2,
                  int n0, int n1, int n2, int* __restrict__ blockHist,
                  float* __restrict__ z)
{
    __shared__ __align__(16) char smem[32768];
    int b = blockIdx.x;
    int tid = threadIdx.x;
    if (b < 12) {
        short* lds_a = (short*)smem;   // [kk*4+kc][row][8]
        int t = b / 6, rb = b % 6;
        const float* W = hWee + t * (128 * 64);
        {
            int row = tid >> 1, half = tid & 1;
            const float4* src = (const float4*)(elec + (size_t)(rb * 128 + row) * 128 + half * 64);
            #pragma unroll
            for (int c = 0; c < 8; ++c) {
                float4 fa = src[c * 2 + 0], fb = src[c * 2 + 1];
                bf16x8 v;
                v[0] = f2bf(fa.x); v[1] = f2bf(fa.y); v[2] = f2bf(fa.z); v[3] = f2bf(fa.w);
                v[4] = f2bf(fb.x); v[5] = f2bf(fb.y); v[6] = f2bf(fb.z); v[7] = f2bf(fb.w);
                int kk = half * 2 + (c >> 2), kc = c & 3;
                *(bf16x8*)&lds_a[((kk * 4 + kc) * 128 + row) * 8] = v;
            }
        }
        __syncthreads();
        int lane = tid & 63, w = tid >> 6, kc = lane >> 4, cr = lane & 15;
        int col = w * 16 + cr;
        bf16x8 bfrag[4];
        #pragma unroll
        for (int kk = 0; kk < 4; ++kk) {
            bf16x8 v;
            #pragma unroll
            for (int j = 0; j < 8; ++j)
                v[j] = f2bf(W[(kk * 32 + kc * 8 + j) * 64 + col]);
            bfrag[kk] = v;
        }
        float bias = hbee[t * 64 + col];
        float* dst = (t == 0 ? hx0 : hx1);
        f32x4 zero4 = {0.f, 0.f, 0.f, 0.f};
        #pragma unroll
        for (int rt = 0; rt < 8; ++rt) {
            f32x4 acc = zero4;
            #pragma unroll
            for (int kk = 0; kk < 4; ++kk) {
                bf16x8 a = *(const bf16x8*)&lds_a[((kk * 4 + kc) * 128 + rt * 16 + cr) * 8];
                acc = __builtin_amdgcn_mfma_f32_16x16x32_bf16(a, bfrag[kk], acc, 0, 0, 0);
            }
            #pragma unroll
            for (int r = 0; r < 4; ++r) {
                int row = rb * 128 + rt * 16 + kc * 4 + r;
                dst[row * 64 + col] = silu_f(acc[r] + bias);
            }
        }
    } else if (b == 12) {
        // hxn: silu(nuclei @ hWne + hbne), 32x64 @ 64x64 (tiny, scalar)
        int lr = tid >> 6, col = tid & 63;
        for (int i = 0; i < 8; ++i) {
            int row = lr * 8 + i;
            float acc = 0.f;
            for (int k = 0; k < 64; ++k)
                acc += nuclei[row * 64 + k] * hWne[k * 64 + col];
            hxn[row * 64 + col] = silu_f(acc + hbne[col]);
        }
    } else if (b == 13) {
        // ufragT: A-fragment of uW^T: A[ucol=tr*16+cr][k=featcol=lg*8+j]
        for (int idx = tid; idx < 3 * 4 * 64; idx += 256) {
            int lane = idx & 63, tr = (idx >> 6) & 3, ty = idx >> 8;
            int lg = lane >> 4, cr = lane & 15;
            for (int j = 0; j < 8; ++j)
                ufragT[idx * 8 + j] =
                    f2bf(uW[(ty * EDGE_INx + lg * 8 + j) * TPSx + tr * 16 + cr]);
        }
        // wWfrag: B-fragment of wW: B[k=ks*32+lg*8+j][col=tn*16+cr]
        for (int idx = tid; idx < 3 * 2 * 4 * 64; idx += 256) {
            int lane = idx & 63, ct = (idx >> 6) & 3, ks = (idx >> 8) & 1, ty = idx >> 9;
            for (int j = 0; j < 8; ++j) {
                int k = ks * 32 + (lane >> 4) * 8 + j, col = ct * 16 + (lane & 15);
                wWfrag[idx * 8 + j] = f2bf(wW[(ty * 64 + k) * 64 + col]);
            }
        }
    } else {
        // blockhist for sort + fold-in z zeroing
        int* h = (int*)smem;
        int bb = b - 14;
        for (int i = bb * 256 + tid; i < 3 * N_ELx * TPSx; i += NB_SORT * 256)
            z[i] = 0.f;
        for (int i = tid; i < NBINS; i += 256) h[i] = 0;
        __syncthreads();
        int total = n0 + n1 + n2;
        int chunk = (total + NB_SORT - 1) / NB_SORT;
        int start = bb * chunk, end = min(start + chunk, total);
        for (int i = start + tid; i < end; i += 256) {
            int t, j;
            if (i < n0)            { t = 0; j = i; }
            else if (i < n0 + n1)  { t = 1; j = i - n0; }
            else                   { t = 2; j = i - n0 - n1; }
            int rv = (t == 0 ? r0 : (t == 1 ? r1 : r2))[j];
            atomicAdd(&h[t * 768 + rv], 1);
        }
        __syncthreads();
        for (int i = tid; i < NBINS; i += 256)
            blockHist[i * NB_SORT + bb] = h[i];
    }
}

// ---------------- sort: scan + scatter (contention-free) ---------------------
__global__ __launch_bounds__(256)
void binscan_kernel(int* __restrict__ blockHist, int* __restrict__ binTotal)
{
    int bin = blockIdx.x * 256 + threadIdx.x;
    int* p = blockHist + bin * NB_SORT;
    int run = 0;
    for (int b = 0; b < NB_SORT; ++b) { int v = p[b]; p[b] = run; run += v; }
    binTotal[bin] = run;
}

__global__ __launch_bounds__(256)
void scan_kernel(const int* __restrict__ bins, int* __restrict__ cursor)
{
    __shared__ int part[256];
    int tid = threadIdx.x;
    int l[9]; int s = 0;
    #pragma unroll
    for (int j = 0; j < 9; ++j) { l[j] = bins[tid * 9 + j]; s += l[j]; }
    part[tid] = s;
    __syncthreads();
    for (int off = 1; off < 256; off <<= 1) {
        int v = (tid >= off) ? part[tid - off] : 0;
        __syncthreads();
        part[tid] += v;
        __syncthreads();
    }
    int run = (tid == 0) ? 0 : part[tid - 1];
    #pragma unroll
    for (int j = 0; j < 9; ++j) { cursor[tid * 9 + j] = run; run += l[j]; }
}

__global__ __launch_bounds__(256)
void scatter2_kernel(const int* __restrict__ r0, const int* __restrict__ r1,
                     const int* __restrict__ r2,
                     int n0, int n1, int n2,
                     const int* __restrict__ blockHist,
                     const int* __restrict__ binStart,
                     int* __restrict__ perm)
{
    __shared__ int cursor[NBINS];
    int tid = threadIdx.x, b = blockIdx.x;
    for (int i = tid; i < NBINS; i += 256)
        cursor[i] = binStart[i] + blockHist[i * NB_SORT + b];
    __syncthreads();
    int total = n0 + n1 + n2;
    int chunk = (total + NB_SORT - 1) / NB_SORT;
    int start = b * chunk, end = min(start + chunk, total);
    for (int i = start + tid; i < end; i += 256) {
        int t, j;
        if (i < n0)            { t = 0; j = i; }
        else if (i < n0 + n1)  { t = 1; j = i - n0; }
        else                   { t = 2; j = i - n0 - n1; }
        int rv = (t == 0 ? r0 : (t == 1 ? r1 : r2))[j];
        int pos = atomicAdd(&cursor[t * 768 + rv], 1);
        perm[pos] = j;
    }
}

// ---------------- edge kernel: register pipeline, 128 edges/wave -------------
// GEMM1 (swapped): e^T = mfma(A = uW^T frag, B = feat^T from global)
// redistribute (16 shfl + 8 sel / 16-edge tile) -> A-frag of e
// GEMM2 (normal): we = mfma(A = e frag, B = wWfrag)  (edges register-local)
// epilogue: silu * hx[sender]; segment reduce: regs over r, 2 shfl_xor over lg
// meta: lane owns 2 edges (ebase + s*64 + lane); per-tile meta via shfl.
__global__ __launch_bounds__(256)
void edge_kernel(const float* __restrict__ feat0, const float* __restrict__ feat1,
                 const float* __restrict__ feat2,
                 const int* __restrict__ s0, const int* __restrict__ s1, const int* __restrict__ s2,
                 const int* __restrict__ r0, const int* __restrict__ r1, const int* __restrict__ r2,
                 const float* __restrict__ u_b, const float* __restrict__ w_b,
                 const float* __restrict__ hx0, const float* __restrict__ hx1,
                 const float* __restrict__ hxn,
                 const short* __restrict__ ufragT, const short* __restrict__ wWfrag,
                 const int* __restrict__ perm,
                 float* __restrict__ z,
                 int n0, int n1, int n2, int nb0, int nb1)
{
    int b = blockIdx.x;
    int t; const float* feat; const int* sn; const int* rc; const float* hx; int nE;
    if (b < nb0)            { t = 0; feat = feat0; sn = s0; rc = r0; hx = hx0; nE = n0; }
    else if (b < nb0 + nb1) { t = 1; b -= nb0; feat = feat1; sn = s1; rc = r1; hx = hx1; nE = n1; }
    else                    { t = 2; b -= nb0 + nb1; feat = feat2; sn = s2; rc = r2; hx = hxn; nE = n2; }

    int tid = threadIdx.x;
    int w = tid >> 6, lane = tid & 63, lg = lane >> 4, cr = lane & 15;
    int ebase = b * EPB + w * 128;
    int t_off = (t == 0) ? 0 : (t == 1 ? n0 : n0 + n1);
    float* zt = z + t * (N_ELx * TPSx);

    // weight fragments + biases (L1-hot broadcast loads), amortized over 128 edges
    bf16x8 uf[4];
    #pragma unroll
    for (int tr = 0; tr < 4; ++tr)
        uf[tr] = *(const bf16x8*)(ufragT + ((t * 4 + tr) * 64 + lane) * 8);
    bf16x8 wf[4][2];
    #pragma unroll
    for (int tn = 0; tn < 4; ++tn)
        #pragma unroll
        for (int ks = 0; ks < 2; ++ks)
            wf[tn][ks] = *(const bf16x8*)(wWfrag + (((t * 2 + ks) * 4 + tn) * 64 + lane) * 8);
    float4 ubv[4];
    #pragma unroll
    for (int tr = 0; tr < 4; ++tr)
        ubv[tr] = *(const float4*)(u_b + t * 64 + tr * 16 + lg * 4);
    float wbv[4];
    #pragma unroll
    for (int tn = 0; tn < 4; ++tn)
        wbv[tn] = w_b[t * 64 + tn * 16 + cr];

    // own-edge meta: lane owns edges ebase + s*64 + lane
    int pe_own[2], s_own[2], r_own[2];
    #pragma unroll
    for (int s = 0; s < 2; ++s) {
        int e = ebase + s * 64 + lane;
        int pe = perm[t_off + min(e, nE - 1)];
        pe_own[s] = pe;
        s_own[s] = sn[pe];
        r_own[s] = rc[pe];
    }

    const int srcA = ((lg & 1) * 2) * 16 + cr;
    const int srcB = srcA + 16;
    const bool selLow = (lg < 2);
    f32x4 zero4 = {0.f, 0.f, 0.f, 0.f};

    #pragma unroll 1
    for (int tc = 0; tc < 8; ++tc) {
        int slot = tc >> 2;
        int b16 = (tc & 3) * 16;

        // ---- per-tile meta via shfl ----
        int pF = __shfl(pe_own[slot], b16 + cr, 64);
        int sidv[4];
        #pragma unroll
        for (int r = 0; r < 4; ++r)
            sidv[r] = __shfl(s_own[slot], b16 + lg * 4 + r, 64);
        bool aE[4];
        #pragma unroll
        for (int r = 0; r < 4; ++r)
            aE[r] = (ebase + tc * 16 + lg * 4 + r) < nE;
        int rF = __shfl(r_own[slot], b16, 64);
        int rL = __shfl(r_own[slot], b16 + 15, 64);

        // ---- feat B-frag straight from global: feat[edge=cr][featcol=lg*8+j] ----
        const float4* fp = (const float4*)(feat + (size_t)pF * EDGE_INx + lg * 8);
        float4 fa = fp[0], fc = fp[1];
        bf16x8 fB = mk8(pk_rnd(fa.x, fa.y), pk_rnd(fa.z, fa.w),
                        pk_rnd(fc.x, fc.y), pk_rnd(fc.z, fc.w));

        // ---- GEMM1: e^T tiles ----
        f32x4 d1[4];
        #pragma unroll
        for (int tr = 0; tr < 4; ++tr)
            d1[tr] = __builtin_amdgcn_mfma_f32_16x16x32_bf16(uf[tr], fB, zero4, 0, 0, 0);

        // ---- silu + pack pairs ----
        uint32_t pk1[4][2];
        #pragma unroll
        for (int tr = 0; tr < 4; ++tr) {
            float v0 = silu_f(d1[tr][0] + ubv[tr].x);
            float v1 = silu_f(d1[tr][1] + ubv[tr].y);
            float v2 = silu_f(d1[tr][2] + ubv[tr].z);
            float v3 = silu_f(d1[tr][3] + ubv[tr].w);
            pk1[tr][0] = pk_rnd(v0, v1);
            pk1[tr][1] = pk_rnd(v2, v3);
        }

        // ---- redistribute -> A-frag of e: lane needs e[edge=cr][ucol=32ks+8lg+j] ----
        bf16x8 ebf[2];
        #pragma unroll
        for (int ks = 0; ks < 2; ++ks) {
            int t0 = 2 * ks, t1 = 2 * ks + 1;
            uint32_t a0 = (uint32_t)__shfl((int)pk1[t0][0], srcA, 64);
            uint32_t b0 = (uint32_t)__shfl((int)pk1[t1][0], srcA, 64);
            uint32_t a1 = (uint32_t)__shfl((int)pk1[t0][1], srcA, 64);
            uint32_t b1 = (uint32_t)__shfl((int)pk1[t1][1], srcA, 64);
            uint32_t a2 = (uint32_t)__shfl((int)pk1[t0][0], srcB, 64);
            uint32_t b2 = (uint32_t)__shfl((int)pk1[t1][0], srcB, 64);
            uint32_t a3 = (uint32_t)__shfl((int)pk1[t0][1], srcB, 64);
            uint32_t b3 = (uint32_t)__shfl((int)pk1[t1][1], srcB, 64);
            ebf[ks] = mk8(selLow ? a0 : b0, selLow ? a1 : b1,
                          selLow ? a2 : b2, selLow ? a3 : b3);
        }

        // ---- hx gather (independent of GEMM2 -> overlaps MFMA) ----
        float hv[4][4];   // [tn][r]
        #pragma unroll
        for (int r = 0; r < 4; ++r) {
            const float* hp = hx + sidv[r] * TPSx + cr;
            #pragma unroll
            for (int tn = 0; tn < 4; ++tn)
                hv[tn][r] = aE[r] ? hp[tn * 16] : 0.f;
        }

        // ---- GEMM2: we tiles ----
        f32x4 d2[4];
        #pragma unroll
        for (int tn = 0; tn < 4; ++tn) {
            f32x4 acc = __builtin_amdgcn_mfma_f32_16x16x32_bf16(ebf[0], wf[tn][0], zero4, 0, 0, 0);
            d2[tn] = __builtin_amdgcn_mfma_f32_16x16x32_bf16(ebf[1], wf[tn][1], acc, 0, 0, 0);
        }

        // ---- message values ----
        float m[4][4];   // [tn][r]
        #pragma unroll
        for (int tn = 0; tn < 4; ++tn)
            #pragma unroll
            for (int r = 0; r < 4; ++r)
                m[tn][r] = silu_f(d2[tn][r] + wbv[tn]) * hv[tn][r];

        // ---- segment reduction over the 16 sorted edges of this tile ----
        if (rF == rL) {
            #pragma unroll
            for (int tn = 0; tn < 4; ++tn) {
                float v = (m[tn][0] + m[tn][1]) + (m[tn][2] + m[tn][3]);
                v += __shfl_xor(v, 16, 64);
                v += __shfl_xor(v, 32, 64);
                if (lg == 0) atomicAdd(&zt[rF * 64 + tn * 16 + cr], v);
            }
        } else {
            int ridv[4];
            #pragma unroll
            for (int r = 0; r < 4; ++r)
                ridv[r] = __shfl(r_own[slot], b16 + lg * 4 + r, 64);
            float a0 = m[0][0], a1 = m[1][0], a2 = m[2][0], a3 = m[3][0];
            int curR = ridv[0];
            #pragma unroll
            for (int r = 1; r < 4; ++r) {
                if (ridv[r] != curR) {
                    atomicAdd(&zt[curR * 64 +  0 + cr], a0);
                    atomicAdd(&zt[curR * 64 + 16 + cr], a1);
                    atomicAdd(&zt[curR * 64 + 32 + cr], a2);
                    atomicAdd(&zt[curR * 64 + 48 + cr], a3);
                    a0 = m[0][r]; a1 = m[1][r]; a2 = m[2][r]; a3 = m[3][r];
                    curR = ridv[r];
                } else {
                    a0 += m[0][r]; a1 += m[1][r]; a2 += m[2][r]; a3 += m[3][r];
                }
            }
            atomicAdd(&zt[curR * 64 +  0 + cr], a0);
            atomicAdd(&zt[curR * 64 + 16 + cr], a1);
            atomicAdd(&zt[curR * 64 + 32 + cr], a2);
            atomicAdd(&zt[curR * 64 + 48 + cr], a3);
        }
    }
}

// ---------------- final kernel: g-subnets + residual ----------------
__global__ __launch_bounds__(128)
void final_kernel(const float* __restrict__ elec, const float* __restrict__ z,
                  const float* __restrict__ gWres, const float* __restrict__ gbres,
                  const float* __restrict__ gWz, const float* __restrict__ gbz,
                  float* __restrict__ out)
{
    __shared__ float xe[4 * 128];
    __shared__ float xz[3 * 4 * 64];
    int b = blockIdx.x;
    int tid = threadIdx.x;
    int row0 = b * 4;
    for (int i = tid; i < 4 * 128; i += 128)
        xe[i] = elec[row0 * 128 + i];
    for (int i = tid; i < 3 * 4 * 64; i += 128) {
        int t = i >> 8; int rr = (i >> 6) & 3; int k = i & 63;
        xz[i] = z[t * N_ELx * 64 + (row0 + rr) * 64 + k];
    }
    __syncthreads();

    int col = tid;
    float accr[4] = {0.f, 0.f, 0.f, 0.f};
    for (int k = 0; k < 128; ++k) {
        float wv = gWres[k * 128 + col];
        #pragma unroll
        for (int r = 0; r < 4; ++r) accr[r] += xe[r * 128 + k] * wv;
    }
    float o[4];
    float br = gbres[col];
    #pragma unroll
    for (int r = 0; r < 4; ++r) o[r] = silu_f(accr[r] + br) + xe[r * 128 + col];

    for (int t = 0; t < 3; ++t) {
        float accz[4] = {0.f, 0.f, 0.f, 0.f};
        for (int k = 0; k < 64; ++k) {
            float wv = gWz[(t * 64 + k) * 128 + col];
            #pragma unroll
            for (int r = 0; r < 4; ++r) accz[r] += xz[t * 256 + r * 64 + k] * wv;
        }
        float bz = gbz[t * 128 + col];
        #pragma unroll
        for (int r = 0; r < 4; ++r) o[r] += silu_f(accz[r] + bz);
    }
    #pragma unroll
    for (int r = 0; r < 4; ++r) out[(row0 + r) * 128 + col] = o[r];
}

extern "C" void kernel_launch(void* const* d_in, const int* in_sizes, int n_in,
                              void* d_out, int out_size, void* d_ws, size_t ws_size,
                              hipStream_t stream)
{
    const float* elec   = (const float*)d_in[0];
    const float* nuclei = (const float*)d_in[1];
    const float* feat0  = (const float*)d_in[2];
    const float* feat1  = (const float*)d_in[3];
    const float* feat2  = (const float*)d_in[4];
    const int*   s0     = (const int*)d_in[5];
    const int*   r0     = (const int*)d_in[6];
    const int*   s1     = (const int*)d_in[7];
    const int*   r1     = (const int*)d_in[8];
    const int*   s2     = (const int*)d_in[9];
    const int*   r2     = (const int*)d_in[10];
    const float* u_W    = (const float*)d_in[11];
    const float* u_b    = (const float*)d_in[12];
    const float* w_W    = (const float*)d_in[13];
    const float* w_b    = (const float*)d_in[14];
    const float* hWee   = (const float*)d_in[15];
    const float* hbee   = (const float*)d_in[16];
    const float* hWne   = (const float*)d_in[17];
    const float* hbne   = (const float*)d_in[18];
    const float* gWres  = (const float*)d_in[19];
    const float* gbres  = (const float*)d_in[20];
    const float* gWz    = (const float*)d_in[21];
    const float* gbz    = (const float*)d_in[22];
    float* out = (float*)d_out;

    char* ws = (char*)d_ws;
    float* hx0      = (float*)(ws + 0);           // 196608
    float* hx1      = (float*)(ws + 196608);      // 196608
    float* hxn      = (float*)(ws + 393216);      // 8192
    float* z        = (float*)(ws + 401408);      // 589824
    short* ufragT   = (short*)(ws + 991232);      // 12288
    short* wWfrag   = (short*)(ws + 1003520);     // 24576
    int*   binTotal = (int*)(ws + 1028096);       // 9216
    int*   binStart = (int*)(ws + 1037312);       // 9216
    int*   perm     = (int*)(ws + 1046528);       // 2454528
    int*   blockHist= (int*)(ws + 3501056);       // 884736  (end: 4385792)

    int n0 = in_sizes[2] / EDGE_INx;
    int n1 = in_sizes[3] / EDGE_INx;
    int n2 = in_sizes[4] / EDGE_INx;
    int nb0 = (n0 + EPB - 1) / EPB;
    int nb1 = (n1 + EPB - 1) / EPB;
    int nb2 = (n2 + EPB - 1) / EPB;

    setup_kernel<<<14 + NB_SORT, 256, 0, stream>>>(
        elec, nuclei, u_W, w_W, hWee, hbee, hWne, hbne,
        hx0, hx1, hxn, ufragT, wWfrag,
        r0, r1, r2, n0, n1, n2, blockHist, z);
    binscan_kernel<<<NBINS / 256, 256, 0, stream>>>(blockHist, binTotal);
    scan_kernel<<<1, 256, 0, stream>>>(binTotal, binStart);
    scatter2_kernel<<<NB_SORT, 256, 0, stream>>>(r0, r1, r2, n0, n1, n2,
                                                 blockHist, binStart, perm);
    edge_kernel<<<nb0 + nb1 + nb2, 256, 0, stream>>>(
        feat0, feat1, feat2, s0, s1, s2, r0, r1, r2,
        u_b, w_b, hx0, hx1, hxn, ufragT, wWfrag, perm, z,
        n0, n1, n2, nb0, nb1);
    final_kernel<<<192, 128, 0, stream>>>(elec, z, gWres, gbres, gWz, gbz, out);
}

// Round 8
// 125.040 us; speedup vs baseline: 1.2456x; 1.0389x over previous
//
#include <hip/hip_runtime.h>
#include <hip/hip_bf16.h>
#include <stdint.h>

#define N_ELx 768
#define EMBx 128
#define TPSx 64
#define EDGE_INx 32
#define EPB 512            // edges per block (4 waves x 128)
#define NBINS 2304         // 3 types * 768 receivers
#define NB_SORT 96

typedef __attribute__((ext_vector_type(8))) short bf16x8;
typedef __attribute__((ext_vector_type(4))) float f32x4;
typedef __attribute__((ext_vector_type(4))) uint32_t u32x4;

__device__ __forceinline__ short f2bf(float f) {
    union { float f; uint32_t u; } v; v.f = f;
    uint32_t u = v.u;
    uint32_t r = (u + 0x7FFFu + ((u >> 16) & 1u)) >> 16;
    return (short)r;
}

// pack 2 floats -> 2 bf16 in one u32 (round-half-up: +0x8000 then byte-perm)
__device__ __forceinline__ uint32_t pk_rnd(float a, float b) {
    uint32_t ua = __float_as_uint(a) + 0x8000u;
    uint32_t ub = __float_as_uint(b) + 0x8000u;
    return __builtin_amdgcn_perm(ub, ua, 0x07060302);
}

__device__ __forceinline__ bf16x8 mk8(uint32_t a, uint32_t b, uint32_t c, uint32_t d) {
    union { u32x4 u; bf16x8 h; } x;
    x.u = (u32x4){a, b, c, d};
    return x.h;
}

__device__ __forceinline__ float silu_f(float x) {
    return x / (1.0f + __expf(-x));
}

// ---------------- setup kernel: prep (blocks 0..13) + blockhist (14..109) ----
__global__ __launch_bounds__(256)
void setup_kernel(const float* __restrict__ elec, const float* __restrict__ nuclei,
                  const float* __restrict__ uW, const float* __restrict__ wW,
                  const float* __restrict__ hWee, const float* __restrict__ hbee,
                  const float* __restrict__ hWne, const float* __restrict__ hbne,
                  float* __restrict__ hx0, float* __restrict__ hx1, float* __restrict__ hxn,
                  short* __restrict__ ufragT, short* __restrict__ wWfrag,
                  const int* __restrict__ r0, const int* __restrict__ r1,
                  const int* __restrict__ r2,
                  int n0, int n1, int n2, int* __restrict__ blockHist,
                  float* __restrict__ z)
{
    __shared__ __align__(16) char smem[32768];
    int b = blockIdx.x;
    int tid = threadIdx.x;
    if (b < 12) {
        short* lds_a = (short*)smem;   // [kk*4+kc][row][8]
        int t = b / 6, rb = b % 6;
        const float* W = hWee + t * (128 * 64);
        {
            int row = tid >> 1, half = tid & 1;
            const float4* src = (const float4*)(elec + (size_t)(rb * 128 + row) * 128 + half * 64);
            #pragma unroll
            for (int c = 0; c < 8; ++c) {
                float4 fa = src[c * 2 + 0], fb = src[c * 2 + 1];
                bf16x8 v;
                v[0] = f2bf(fa.x); v[1] = f2bf(fa.y); v[2] = f2bf(fa.z); v[3] = f2bf(fa.w);
                v[4] = f2bf(fb.x); v[5] = f2bf(fb.y); v[6] = f2bf(fb.z); v[7] = f2bf(fb.w);
                int kk = half * 2 + (c >> 2), kc = c & 3;
                *(bf16x8*)&lds_a[((kk * 4 + kc) * 128 + row) * 8] = v;
            }
        }
        __syncthreads();
        int lane = tid & 63, w = tid >> 6, kc = lane >> 4, cr = lane & 15;
        int col = w * 16 + cr;
        bf16x8 bfrag[4];
        #pragma unroll
        for (int kk = 0; kk < 4; ++kk) {
            bf16x8 v;
            #pragma unroll
            for (int j = 0; j < 8; ++j)
                v[j] = f2bf(W[(kk * 32 + kc * 8 + j) * 64 + col]);
            bfrag[kk] = v;
        }
        float bias = hbee[t * 64 + col];
        float* dst = (t == 0 ? hx0 : hx1);
        f32x4 zero4 = {0.f, 0.f, 0.f, 0.f};
        #pragma unroll
        for (int rt = 0; rt < 8; ++rt) {
            f32x4 acc = zero4;
            #pragma unroll
            for (int kk = 0; kk < 4; ++kk) {
                bf16x8 a = *(const bf16x8*)&lds_a[((kk * 4 + kc) * 128 + rt * 16 + cr) * 8];
                acc = __builtin_amdgcn_mfma_f32_16x16x32_bf16(a, bfrag[kk], acc, 0, 0, 0);
            }
            #pragma unroll
            for (int r = 0; r < 4; ++r) {
                int row = rb * 128 + rt * 16 + kc * 4 + r;
                dst[row * 64 + col] = silu_f(acc[r] + bias);
            }
        }
    } else if (b == 12) {
        // hxn: silu(nuclei @ hWne + hbne), 32x64 @ 64x64 (tiny, scalar)
        int lr = tid >> 6, col = tid & 63;
        for (int i = 0; i < 8; ++i) {
            int row = lr * 8 + i;
            float acc = 0.f;
            for (int k = 0; k < 64; ++k)
                acc += nuclei[row * 64 + k] * hWne[k * 64 + col];
            hxn[row * 64 + col] = silu_f(acc + hbne[col]);
        }
    } else if (b == 13) {
        // ufragT: A-fragment of uW^T: A[ucol=tr*16+cr][k=featcol=lg*8+j]
        for (int idx = tid; idx < 3 * 4 * 64; idx += 256) {
            int lane = idx & 63, tr = (idx >> 6) & 3, ty = idx >> 8;
            int lg = lane >> 4, cr = lane & 15;
            for (int j = 0; j < 8; ++j)
                ufragT[idx * 8 + j] =
                    f2bf(uW[(ty * EDGE_INx + lg * 8 + j) * TPSx + tr * 16 + cr]);
        }
        // wWfrag: B-fragment of wW: B[k=ks*32+lg*8+j][col=tn*16+cr]
        for (int idx = tid; idx < 3 * 2 * 4 * 64; idx += 256) {
            int lane = idx & 63, ct = (idx >> 6) & 3, ks = (idx >> 8) & 1, ty = idx >> 9;
            for (int j = 0; j < 8; ++j) {
                int k = ks * 32 + (lane >> 4) * 8 + j, col = ct * 16 + (lane & 15);
                wWfrag[idx * 8 + j] = f2bf(wW[(ty * 64 + k) * 64 + col]);
            }
        }
    } else {
        // blockhist for sort + fold-in z zeroing
        int* h = (int*)smem;
        int bb = b - 14;
        for (int i = bb * 256 + tid; i < 3 * N_ELx * TPSx; i += NB_SORT * 256)
            z[i] = 0.f;
        for (int i = tid; i < NBINS; i += 256) h[i] = 0;
        __syncthreads();
        int total = n0 + n1 + n2;
        int chunk = (total + NB_SORT - 1) / NB_SORT;
        int start = bb * chunk, end = min(start + chunk, total);
        for (int i = start + tid; i < end; i += 256) {
            int t, j;
            if (i < n0)            { t = 0; j = i; }
            else if (i < n0 + n1)  { t = 1; j = i - n0; }
            else                   { t = 2; j = i - n0 - n1; }
            int rv = (t == 0 ? r0 : (t == 1 ? r1 : r2))[j];
            atomicAdd(&h[t * 768 + rv], 1);
        }
        __syncthreads();
        for (int i = tid; i < NBINS; i += 256)
            blockHist[i * NB_SORT + bb] = h[i];
    }
}

// ---------------- sort: scan + scatter (contention-free) ---------------------
__global__ __launch_bounds__(256)
void binscan_kernel(int* __restrict__ blockHist, int* __restrict__ binTotal)
{
    int bin = blockIdx.x * 256 + threadIdx.x;
    int* p = blockHist + bin * NB_SORT;
    int run = 0;
    for (int b = 0; b < NB_SORT; ++b) { int v = p[b]; p[b] = run; run += v; }
    binTotal[bin] = run;
}

__global__ __launch_bounds__(256)
void scan_kernel(const int* __restrict__ bins, int* __restrict__ cursor)
{
    __shared__ int part[256];
    int tid = threadIdx.x;
    int l[9]; int s = 0;
    #pragma unroll
    for (int j = 0; j < 9; ++j) { l[j] = bins[tid * 9 + j]; s += l[j]; }
    part[tid] = s;
    __syncthreads();
    for (int off = 1; off < 256; off <<= 1) {
        int v = (tid >= off) ? part[tid - off] : 0;
        __syncthreads();
        part[tid] += v;
        __syncthreads();
    }
    int run = (tid == 0) ? 0 : part[tid - 1];
    #pragma unroll
    for (int j = 0; j < 9; ++j) { cursor[tid * 9 + j] = run; run += l[j]; }
}

__global__ __launch_bounds__(256)
void scatter2_kernel(const int* __restrict__ r0, const int* __restrict__ r1,
                     const int* __restrict__ r2,
                     int n0, int n1, int n2,
                     const int* __restrict__ blockHist,
                     const int* __restrict__ binStart,
                     int* __restrict__ perm)
{
    __shared__ int cursor[NBINS];
    int tid = threadIdx.x, b = blockIdx.x;
    for (int i = tid; i < NBINS; i += 256)
        cursor[i] = binStart[i] + blockHist[i * NB_SORT + b];
    __syncthreads();
    int total = n0 + n1 + n2;
    int chunk = (total + NB_SORT - 1) / NB_SORT;
    int start = b * chunk, end = min(start + chunk, total);
    for (int i = start + tid; i < end; i += 256) {
        int t, j;
        if (i < n0)            { t = 0; j = i; }
        else if (i < n0 + n1)  { t = 1; j = i - n0; }
        else                   { t = 2; j = i - n0 - n1; }
        int rv = (t == 0 ? r0 : (t == 1 ? r1 : r2))[j];
        int pos = atomicAdd(&cursor[t * 768 + rv], 1);
        perm[pos] = j;
    }
}

// ---------------- edge kernel: register pipeline + depth-2 feat prefetch -----
// GEMM1 (swapped): e^T = mfma(A = uW^T frag, B = feat^T from global)
// redistribute (16 shfl + 8 sel / 16-edge tile) -> A-frag of e
// GEMM2 (normal): we = mfma(A = e frag, B = wWfrag)  (edges register-local)
// epilogue: silu * hx[sender]; segment reduce: regs over r, 2 shfl_xor over lg
// pipeline: feat loads for tile tc+1 issued before compute of tile tc (T14);
// hx gathers issued before GEMM1, consumed after GEMM2.
__global__ __launch_bounds__(256)
void edge_kernel(const float* __restrict__ feat0, const float* __restrict__ feat1,
                 const float* __restrict__ feat2,
                 const int* __restrict__ s0, const int* __restrict__ s1, const int* __restrict__ s2,
                 const int* __restrict__ r0, const int* __restrict__ r1, const int* __restrict__ r2,
                 const float* __restrict__ u_b, const float* __restrict__ w_b,
                 const float* __restrict__ hx0, const float* __restrict__ hx1,
                 const float* __restrict__ hxn,
                 const short* __restrict__ ufragT, const short* __restrict__ wWfrag,
                 const int* __restrict__ perm,
                 float* __restrict__ z,
                 int n0, int n1, int n2, int nb0, int nb1)
{
    int b = blockIdx.x;
    int t; const float* feat; const int* sn; const int* rc; const float* hx; int nE;
    if (b < nb0)            { t = 0; feat = feat0; sn = s0; rc = r0; hx = hx0; nE = n0; }
    else if (b < nb0 + nb1) { t = 1; b -= nb0; feat = feat1; sn = s1; rc = r1; hx = hx1; nE = n1; }
    else                    { t = 2; b -= nb0 + nb1; feat = feat2; sn = s2; rc = r2; hx = hxn; nE = n2; }

    int tid = threadIdx.x;
    int w = tid >> 6, lane = tid & 63, lg = lane >> 4, cr = lane & 15;
    int ebase = b * EPB + w * 128;
    if (ebase >= nE) return;                    // fully-empty wave (no barriers used)
    bool partial = (ebase + 128 > nE);          // never true for this problem's sizes
    int t_off = (t == 0) ? 0 : (t == 1 ? n0 : n0 + n1);
    float* zt = z + t * (N_ELx * TPSx);

    // weight fragments + biases (L1-hot broadcast loads), amortized over 128 edges
    bf16x8 uf[4];
    #pragma unroll
    for (int tr = 0; tr < 4; ++tr)
        uf[tr] = *(const bf16x8*)(ufragT + ((t * 4 + tr) * 64 + lane) * 8);
    bf16x8 wf[4][2];
    #pragma unroll
    for (int tn = 0; tn < 4; ++tn)
        #pragma unroll
        for (int ks = 0; ks < 2; ++ks)
            wf[tn][ks] = *(const bf16x8*)(wWfrag + (((t * 2 + ks) * 4 + tn) * 64 + lane) * 8);
    float4 ubv[4];
    #pragma unroll
    for (int tr = 0; tr < 4; ++tr)
        ubv[tr] = *(const float4*)(u_b + t * 64 + tr * 16 + lg * 4);
    float wbv[4];
    #pragma unroll
    for (int tn = 0; tn < 4; ++tn)
        wbv[tn] = w_b[t * 64 + tn * 16 + cr];

    // own-edge meta (explicit scalars — avoid runtime-indexed arrays, rule #20)
    int pe_own0, pe_own1, s_own0, s_own1, r_own0, r_own1;
    {
        int e0i = ebase + lane;
        int e1i = ebase + 64 + lane;
        pe_own0 = perm[t_off + min(e0i, nE - 1)];
        pe_own1 = perm[t_off + min(e1i, nE - 1)];
        s_own0 = sn[pe_own0]; r_own0 = rc[pe_own0];
        s_own1 = sn[pe_own1]; r_own1 = rc[pe_own1];
    }

    const int srcA = ((lg & 1) * 2) * 16 + cr;
    const int srcB = srcA + 16;
    const bool selLow = (lg < 2);
    f32x4 zero4 = {0.f, 0.f, 0.f, 0.f};

    // ---- prologue: prefetch feat for tile 0 ----
    int pF_n = __shfl(pe_own0, cr, 64);
    float4 fa_n, fc_n;
    {
        const float4* fp = (const float4*)(feat + (size_t)pF_n * EDGE_INx + lg * 8);
        fa_n = fp[0]; fc_n = fp[1];
    }

    #pragma unroll 1
    for (int tc = 0; tc < 8; ++tc) {
        int slot_hi = (tc & 4);                  // wave-uniform
        int b16 = (tc & 3) * 16;
        float4 fa = fa_n, fc = fc_n;

        // ---- prefetch feat for tile tc+1 (issue-early, consume next iter) ----
        if (tc < 7) {
            int ntc = tc + 1;
            int npe = ((ntc & 4)) ? pe_own1 : pe_own0;
            pF_n = __shfl(npe, ((ntc & 3) * 16) + cr, 64);
            const float4* fp = (const float4*)(feat + (size_t)pF_n * EDGE_INx + lg * 8);
            fa_n = fp[0]; fc_n = fp[1];
        }

        // ---- per-tile meta via shfl; issue hx gathers early ----
        int s_cur = slot_hi ? s_own1 : s_own0;
        int r_cur = slot_hi ? r_own1 : r_own0;
        int sidv[4];
        #pragma unroll
        for (int r = 0; r < 4; ++r)
            sidv[r] = __shfl(s_cur, b16 + lg * 4 + r, 64);
        int rF = __shfl(r_cur, b16, 64);
        int rL = __shfl(r_cur, b16 + 15, 64);

        float hv[4][4];   // [tn][r] — loads issued here, consumed after GEMM2
        if (!partial) {
            #pragma unroll
            for (int r = 0; r < 4; ++r) {
                const float* hp = hx + sidv[r] * TPSx + cr;
                #pragma unroll
                for (int tn = 0; tn < 4; ++tn)
                    hv[tn][r] = hp[tn * 16];
            }
        } else {
            #pragma unroll
            for (int r = 0; r < 4; ++r) {
                bool aE = (ebase + tc * 16 + lg * 4 + r) < nE;
                const float* hp = hx + sidv[r] * TPSx + cr;
                #pragma unroll
                for (int tn = 0; tn < 4; ++tn)
                    hv[tn][r] = aE ? hp[tn * 16] : 0.f;
            }
        }

        // ---- feat B-frag from prefetched regs: feat[edge=cr][featcol=lg*8+j] ----
        bf16x8 fB = mk8(pk_rnd(fa.x, fa.y), pk_rnd(fa.z, fa.w),
                        pk_rnd(fc.x, fc.y), pk_rnd(fc.z, fc.w));

        // ---- GEMM1: e^T tiles ----
        f32x4 d1[4];
        #pragma unroll
        for (int tr = 0; tr < 4; ++tr)
            d1[tr] = __builtin_amdgcn_mfma_f32_16x16x32_bf16(uf[tr], fB, zero4, 0, 0, 0);

        // ---- silu + pack pairs ----
        uint32_t pk1[4][2];
        #pragma unroll
        for (int tr = 0; tr < 4; ++tr) {
            float v0 = silu_f(d1[tr][0] + ubv[tr].x);
            float v1 = silu_f(d1[tr][1] + ubv[tr].y);
            float v2 = silu_f(d1[tr][2] + ubv[tr].z);
            float v3 = silu_f(d1[tr][3] + ubv[tr].w);
            pk1[tr][0] = pk_rnd(v0, v1);
            pk1[tr][1] = pk_rnd(v2, v3);
        }

        // ---- redistribute -> A-frag of e: lane needs e[edge=cr][ucol=32ks+8lg+j] ----
        bf16x8 ebf[2];
        #pragma unroll
        for (int ks = 0; ks < 2; ++ks) {
            int t0 = 2 * ks, t1 = 2 * ks + 1;
            uint32_t a0 = (uint32_t)__shfl((int)pk1[t0][0], srcA, 64);
            uint32_t b0 = (uint32_t)__shfl((int)pk1[t1][0], srcA, 64);
            uint32_t a1 = (uint32_t)__shfl((int)pk1[t0][1], srcA, 64);
            uint32_t b1 = (uint32_t)__shfl((int)pk1[t1][1], srcA, 64);
            uint32_t a2 = (uint32_t)__shfl((int)pk1[t0][0], srcB, 64);
            uint32_t b2 = (uint32_t)__shfl((int)pk1[t1][0], srcB, 64);
            uint32_t a3 = (uint32_t)__shfl((int)pk1[t0][1], srcB, 64);
            uint32_t b3 = (uint32_t)__shfl((int)pk1[t1][1], srcB, 64);
            ebf[ks] = mk8(selLow ? a0 : b0, selLow ? a1 : b1,
                          selLow ? a2 : b2, selLow ? a3 : b3);
        }

        // ---- GEMM2: we tiles ----
        f32x4 d2[4];
        #pragma unroll
        for (int tn = 0; tn < 4; ++tn) {
            f32x4 acc = __builtin_amdgcn_mfma_f32_16x16x32_bf16(ebf[0], wf[tn][0], zero4, 0, 0, 0);
            d2[tn] = __builtin_amdgcn_mfma_f32_16x16x32_bf16(ebf[1], wf[tn][1], acc, 0, 0, 0);
        }

        // ---- message values (hv consumed here — latency long since issued) ----
        float m[4][4];   // [tn][r]
        #pragma unroll
        for (int tn = 0; tn < 4; ++tn)
            #pragma unroll
            for (int r = 0; r < 4; ++r)
                m[tn][r] = silu_f(d2[tn][r] + wbv[tn]) * hv[tn][r];

        // ---- segment reduction over the 16 sorted edges of this tile ----
        if (rF == rL) {
            #pragma unroll
            for (int tn = 0; tn < 4; ++tn) {
                float v = (m[tn][0] + m[tn][1]) + (m[tn][2] + m[tn][3]);
                v += __shfl_xor(v, 16, 64);
                v += __shfl_xor(v, 32, 64);
                if (lg == 0) atomicAdd(&zt[rF * 64 + tn * 16 + cr], v);
            }
        } else {
            int ridv[4];
            #pragma unroll
            for (int r = 0; r < 4; ++r)
                ridv[r] = __shfl(r_cur, b16 + lg * 4 + r, 64);
            float a0 = m[0][0], a1 = m[1][0], a2 = m[2][0], a3 = m[3][0];
            int curR = ridv[0];
            #pragma unroll
            for (int r = 1; r < 4; ++r) {
                if (ridv[r] != curR) {
                    atomicAdd(&zt[curR * 64 +  0 + cr], a0);
                    atomicAdd(&zt[curR * 64 + 16 + cr], a1);
                    atomicAdd(&zt[curR * 64 + 32 + cr], a2);
                    atomicAdd(&zt[curR * 64 + 48 + cr], a3);
                    a0 = m[0][r]; a1 = m[1][r]; a2 = m[2][r]; a3 = m[3][r];
                    curR = ridv[r];
                } else {
                    a0 += m[0][r]; a1 += m[1][r]; a2 += m[2][r]; a3 += m[3][r];
                }
            }
            atomicAdd(&zt[curR * 64 +  0 + cr], a0);
            atomicAdd(&zt[curR * 64 + 16 + cr], a1);
            atomicAdd(&zt[curR * 64 + 32 + cr], a2);
            atomicAdd(&zt[curR * 64 + 48 + cr], a3);
        }
    }
}

// ---------------- final kernel: g-subnets + residual ----------------
__global__ __launch_bounds__(128)
void final_kernel(const float* __restrict__ elec, const float* __restrict__ z,
                  const float* __restrict__ gWres, const float* __restrict__ gbres,
                  const float* __restrict__ gWz, const float* __restrict__ gbz,
                  float* __restrict__ out)
{
    __shared__ float xe[4 * 128];
    __shared__ float xz[3 * 4 * 64];
    int b = blockIdx.x;
    int tid = threadIdx.x;
    int row0 = b * 4;
    for (int i = tid; i < 4 * 128; i += 128)
        xe[i] = elec[row0 * 128 + i];
    for (int i = tid; i < 3 * 4 * 64; i += 128) {
        int t = i >> 8; int rr = (i >> 6) & 3; int k = i & 63;
        xz[i] = z[t * N_ELx * 64 + (row0 + rr) * 64 + k];
    }
    __syncthreads();

    int col = tid;
    float accr[4] = {0.f, 0.f, 0.f, 0.f};
    for (int k = 0; k < 128; ++k) {
        float wv = gWres[k * 128 + col];
        #pragma unroll
        for (int r = 0; r < 4; ++r) accr[r] += xe[r * 128 + k] * wv;
    }
    float o[4];
    float br = gbres[col];
    #pragma unroll
    for (int r = 0; r < 4; ++r) o[r] = silu_f(accr[r] + br) + xe[r * 128 + col];

    for (int t = 0; t < 3; ++t) {
        float accz[4] = {0.f, 0.f, 0.f, 0.f};
        for (int k = 0; k < 64; ++k) {
            float wv = gWz[(t * 64 + k) * 128 + col];
            #pragma unroll
            for (int r = 0; r < 4; ++r) accz[r] += xz[t * 256 + r * 64 + k] * wv;
        }
        float bz = gbz[t * 128 + col];
        #pragma unroll
        for (int r = 0; r < 4; ++r) o[r] += silu_f(accz[r] + bz);
    }
    #pragma unroll
    for (int r = 0; r < 4; ++r) out[(row0 + r) * 128 + col] = o[r];
}

extern "C" void kernel_launch(void* const* d_in, const int* in_sizes, int n_in,
                              void* d_out, int out_size, void* d_ws, size_t ws_size,
                              hipStream_t stream)
{
    const float* elec   = (const float*)d_in[0];
    const float* nuclei = (const float*)d_in[1];
    const float* feat0  = (const float*)d_in[2];
    const float* feat1  = (const float*)d_in[3];
    const float* feat2  = (const float*)d_in[4];
    const int*   s0     = (const int*)d_in[5];
    const int*   r0     = (const int*)d_in[6];
    const int*   s1     = (const int*)d_in[7];
    const int*   r1     = (const int*)d_in[8];
    const int*   s2     = (const int*)d_in[9];
    const int*   r2     = (const int*)d_in[10];
    const float* u_W    = (const float*)d_in[11];
    const float* u_b    = (const float*)d_in[12];
    const float* w_W    = (const float*)d_in[13];
    const float* w_b    = (const float*)d_in[14];
    const float* hWee   = (const float*)d_in[15];
    const float* hbee   = (const float*)d_in[16];
    const float* hWne   = (const float*)d_in[17];
    const float* hbne   = (const float*)d_in[18];
    const float* gWres  = (const float*)d_in[19];
    const float* gbres  = (const float*)d_in[20];
    const float* gWz    = (const float*)d_in[21];
    const float* gbz    = (const float*)d_in[22];
    float* out = (float*)d_out;

    char* ws = (char*)d_ws;
    float* hx0      = (float*)(ws + 0);           // 196608
    float* hx1      = (float*)(ws + 196608);      // 196608
    float* hxn      = (float*)(ws + 393216);      // 8192
    float* z        = (float*)(ws + 401408);      // 589824
    short* ufragT   = (short*)(ws + 991232);      // 12288
    short* wWfrag   = (short*)(ws + 1003520);     // 24576
    int*   binTotal = (int*)(ws + 1028096);       // 9216
    int*   binStart = (int*)(ws + 1037312);       // 9216
    int*   perm     = (int*)(ws + 1046528);       // 2454528
    int*   blockHist= (int*)(ws + 3501056);       // 884736  (end: 4385792)

    int n0 = in_sizes[2] / EDGE_INx;
    int n1 = in_sizes[3] / EDGE_INx;
    int n2 = in_sizes[4] / EDGE_INx;
    int nb0 = (n0 + EPB - 1) / EPB;
    int nb1 = (n1 + EPB - 1) / EPB;
    int nb2 = (n2 + EPB - 1) / EPB;

    setup_kernel<<<14 + NB_SORT, 256, 0, stream>>>(
        elec, nuclei, u_W, w_W, hWee, hbee, hWne, hbne,
        hx0, hx1, hxn, ufragT, wWfrag,
        r0, r1, r2, n0, n1, n2, blockHist, z);
    binscan_kernel<<<NBINS / 256, 256, 0, stream>>>(blockHist, binTotal);
    scan_kernel<<<1, 256, 0, stream>>>(binTotal, binStart);
    scatter2_kernel<<<NB_SORT, 256, 0, stream>>>(r0, r1, r2, n0, n1, n2,
                                                 blockHist, binStart, perm);
    edge_kernel<<<nb0 + nb1 + nb2, 256, 0, stream>>>(
        feat0, feat1, feat2, s0, s1, s2, r0, r1, r2,
        u_b, w_b, hx0, hx1, hxn, ufragT, wWfrag, perm, z,
        n0, n1, n2, nb0, nb1);
    final_kernel<<<192, 128, 0, stream>>>(elec, z, gWres, gbres, gWz, gbz, out);
}

// Round 9
// 102.522 us; speedup vs baseline: 1.5192x; 1.2196x over previous
//
#include <hip/hip_runtime.h>
#include <hip/hip_bf16.h>
#include <stdint.h>

#define N_ELx 768
#define EMBx 128
#define TPSx 64
#define EDGE_INx 32
#define EPB 512            // edges per block (4 waves x 128)
#define NBINS 2304         // 3 types * 768 receivers
#define NB_SORT 96

typedef __attribute__((ext_vector_type(8))) short bf16x8;
typedef __attribute__((ext_vector_type(4))) float f32x4;
typedef __attribute__((ext_vector_type(4))) uint32_t u32x4;

__device__ __forceinline__ short f2bf(float f) {
    union { float f; uint32_t u; } v; v.f = f;
    uint32_t u = v.u;
    uint32_t r = (u + 0x7FFFu + ((u >> 16) & 1u)) >> 16;
    return (short)r;
}

// 1-instruction packed f32->bf16 pair (lo -> low16, hi -> high16), RNE
__device__ __forceinline__ uint32_t cvtpk(float lo, float hi) {
    uint32_t r;
    asm("v_cvt_pk_bf16_f32 %0, %1, %2" : "=v"(r) : "v"(lo), "v"(hi));
    return r;
}

__device__ __forceinline__ bf16x8 mk8(uint32_t a, uint32_t b, uint32_t c, uint32_t d) {
    union { u32x4 u; bf16x8 h; } x;
    x.u = (u32x4){a, b, c, d};
    return x.h;
}

// fast silu: 5 VALU insts (mul, exp2, add, rcp, mul) — avoids fp32 div sequence
__device__ __forceinline__ float silu_f(float x) {
    float e = __builtin_amdgcn_exp2f(-1.442695041f * x);
    return x * __builtin_amdgcn_rcpf(1.0f + e);
}

// ---------------- setup kernel: prep (blocks 0..13) + blockhist (14..109) ----
__global__ __launch_bounds__(256)
void setup_kernel(const float* __restrict__ elec, const float* __restrict__ nuclei,
                  const float* __restrict__ uW, const float* __restrict__ wW,
                  const float* __restrict__ hWee, const float* __restrict__ hbee,
                  const float* __restrict__ hWne, const float* __restrict__ hbne,
                  float* __restrict__ hx0, float* __restrict__ hx1, float* __restrict__ hxn,
                  short* __restrict__ ufragT, short* __restrict__ wWfrag,
                  const int* __restrict__ r0, const int* __restrict__ r1,
                  const int* __restrict__ r2,
                  int n0, int n1, int n2, int* __restrict__ blockHist,
                  float* __restrict__ z)
{
    __shared__ __align__(16) char smem[32768];
    int b = blockIdx.x;
    int tid = threadIdx.x;
    if (b < 12) {
        short* lds_a = (short*)smem;   // [kk*4+kc][row][8]
        int t = b / 6, rb = b % 6;
        const float* W = hWee + t * (128 * 64);
        {
            int row = tid >> 1, half = tid & 1;
            const float4* src = (const float4*)(elec + (size_t)(rb * 128 + row) * 128 + half * 64);
            #pragma unroll
            for (int c = 0; c < 8; ++c) {
                float4 fa = src[c * 2 + 0], fb = src[c * 2 + 1];
                bf16x8 v;
                v[0] = f2bf(fa.x); v[1] = f2bf(fa.y); v[2] = f2bf(fa.z); v[3] = f2bf(fa.w);
                v[4] = f2bf(fb.x); v[5] = f2bf(fb.y); v[6] = f2bf(fb.z); v[7] = f2bf(fb.w);
                int kk = half * 2 + (c >> 2), kc = c & 3;
                *(bf16x8*)&lds_a[((kk * 4 + kc) * 128 + row) * 8] = v;
            }
        }
        __syncthreads();
        int lane = tid & 63, w = tid >> 6, kc = lane >> 4, cr = lane & 15;
        int col = w * 16 + cr;
        bf16x8 bfrag[4];
        #pragma unroll
        for (int kk = 0; kk < 4; ++kk) {
            bf16x8 v;
            #pragma unroll
            for (int j = 0; j < 8; ++j)
                v[j] = f2bf(W[(kk * 32 + kc * 8 + j) * 64 + col]);
            bfrag[kk] = v;
        }
        float bias = hbee[t * 64 + col];
        float* dst = (t == 0 ? hx0 : hx1);
        f32x4 zero4 = {0.f, 0.f, 0.f, 0.f};
        #pragma unroll
        for (int rt = 0; rt < 8; ++rt) {
            f32x4 acc = zero4;
            #pragma unroll
            for (int kk = 0; kk < 4; ++kk) {
                bf16x8 a = *(const bf16x8*)&lds_a[((kk * 4 + kc) * 128 + rt * 16 + cr) * 8];
                acc = __builtin_amdgcn_mfma_f32_16x16x32_bf16(a, bfrag[kk], acc, 0, 0, 0);
            }
            #pragma unroll
            for (int r = 0; r < 4; ++r) {
                int row = rb * 128 + rt * 16 + kc * 4 + r;
                dst[row * 64 + col] = silu_f(acc[r] + bias);
            }
        }
    } else if (b == 12) {
        // hxn: silu(nuclei @ hWne + hbne), 32x64 @ 64x64 (tiny, scalar)
        int lr = tid >> 6, col = tid & 63;
        for (int i = 0; i < 8; ++i) {
            int row = lr * 8 + i;
            float acc = 0.f;
            for (int k = 0; k < 64; ++k)
                acc += nuclei[row * 64 + k] * hWne[k * 64 + col];
            hxn[row * 64 + col] = silu_f(acc + hbne[col]);
        }
    } else if (b == 13) {
        // ufragT: A-fragment of uW^T: A[ucol=tr*16+cr][k=featcol=lg*8+j]
        for (int idx = tid; idx < 3 * 4 * 64; idx += 256) {
            int lane = idx & 63, tr = (idx >> 6) & 3, ty = idx >> 8;
            int lg = lane >> 4, cr = lane & 15;
            for (int j = 0; j < 8; ++j)
                ufragT[idx * 8 + j] =
                    f2bf(uW[(ty * EDGE_INx + lg * 8 + j) * TPSx + tr * 16 + cr]);
        }
        // wWfrag: B-fragment of wW: B[k=ks*32+lg*8+j][col=tn*16+cr]
        for (int idx = tid; idx < 3 * 2 * 4 * 64; idx += 256) {
            int lane = idx & 63, ct = (idx >> 6) & 3, ks = (idx >> 8) & 1, ty = idx >> 9;
            for (int j = 0; j < 8; ++j) {
                int k = ks * 32 + (lane >> 4) * 8 + j, col = ct * 16 + (lane & 15);
                wWfrag[idx * 8 + j] = f2bf(wW[(ty * 64 + k) * 64 + col]);
            }
        }
    } else {
        // blockhist for sort + fold-in z zeroing
        int* h = (int*)smem;
        int bb = b - 14;
        for (int i = bb * 256 + tid; i < 3 * N_ELx * TPSx; i += NB_SORT * 256)
            z[i] = 0.f;
        for (int i = tid; i < NBINS; i += 256) h[i] = 0;
        __syncthreads();
        int total = n0 + n1 + n2;
        int chunk = (total + NB_SORT - 1) / NB_SORT;
        int start = bb * chunk, end = min(start + chunk, total);
        for (int i = start + tid; i < end; i += 256) {
            int t, j;
            if (i < n0)            { t = 0; j = i; }
            else if (i < n0 + n1)  { t = 1; j = i - n0; }
            else                   { t = 2; j = i - n0 - n1; }
            int rv = (t == 0 ? r0 : (t == 1 ? r1 : r2))[j];
            atomicAdd(&h[t * 768 + rv], 1);
        }
        __syncthreads();
        for (int i = tid; i < NBINS; i += 256)
            blockHist[i * NB_SORT + bb] = h[i];
    }
}

// ---------------- sort: per-bin block scan, then scatter (scan folded in) ----
__global__ __launch_bounds__(256)
void binscan_kernel(int* __restrict__ blockHist, int* __restrict__ binTotal)
{
    int bin = blockIdx.x * 256 + threadIdx.x;
    int* p = blockHist + bin * NB_SORT;
    int run = 0;
    for (int b = 0; b < NB_SORT; ++b) { int v = p[b]; p[b] = run; run += v; }
    binTotal[bin] = run;
}

__global__ __launch_bounds__(256)
void scatter2_kernel(const int* __restrict__ r0, const int* __restrict__ r1,
                     const int* __restrict__ r2,
                     int n0, int n1, int n2,
                     const int* __restrict__ blockHist,
                     const int* __restrict__ binTotal,
                     int* __restrict__ perm)
{
    __shared__ int cursor[NBINS];
    __shared__ int part[256];
    int tid = threadIdx.x, b = blockIdx.x;
    // per-block redundant exclusive scan of binTotal (replaces scan_kernel launch)
    int l[9]; int s = 0;
    #pragma unroll
    for (int j = 0; j < 9; ++j) { l[j] = binTotal[tid * 9 + j]; s += l[j]; }
    part[tid] = s;
    __syncthreads();
    for (int off = 1; off < 256; off <<= 1) {
        int v = (tid >= off) ? part[tid - off] : 0;
        __syncthreads();
        part[tid] += v;
        __syncthreads();
    }
    int run = (tid == 0) ? 0 : part[tid - 1];
    #pragma unroll
    for (int j = 0; j < 9; ++j) {
        int bin = tid * 9 + j;
        cursor[bin] = run + blockHist[bin * NB_SORT + b];
        run += l[j];
    }
    __syncthreads();
    int total = n0 + n1 + n2;
    int chunk = (total + NB_SORT - 1) / NB_SORT;
    int start = b * chunk, end = min(start + chunk, total);
    for (int i = start + tid; i < end; i += 256) {
        int t, j;
        if (i < n0)            { t = 0; j = i; }
        else if (i < n0 + n1)  { t = 1; j = i - n0; }
        else                   { t = 2; j = i - n0 - n1; }
        int rv = (t == 0 ? r0 : (t == 1 ? r1 : r2))[j];
        int pos = atomicAdd(&cursor[t * 768 + rv], 1);
        perm[pos] = j;
    }
}

// ---------------- edge kernel: register pipeline, lean VALU ------------------
// GEMM1 (swapped): e^T = mfma(A = uW^T frag, B = feat^T from global, prefetched)
// redistribute (16 shfl + 8 sel / 16-edge tile) -> A-frag of e
// GEMM2 (normal): we = mfma(A = e frag, B = wWfrag)  (edges register-local)
// epilogue: silu * hx[sender]; per-lane acc across tiles, flush on receiver change
__global__ __launch_bounds__(256)
void edge_kernel(const float* __restrict__ feat0, const float* __restrict__ feat1,
                 const float* __restrict__ feat2,
                 const int* __restrict__ s0, const int* __restrict__ s1, const int* __restrict__ s2,
                 const int* __restrict__ r0, const int* __restrict__ r1, const int* __restrict__ r2,
                 const float* __restrict__ u_b, const float* __restrict__ w_b,
                 const float* __restrict__ hx0, const float* __restrict__ hx1,
                 const float* __restrict__ hxn,
                 const short* __restrict__ ufragT, const short* __restrict__ wWfrag,
                 const int* __restrict__ perm,
                 float* __restrict__ z,
                 int n0, int n1, int n2, int nb0, int nb1)
{
    int b = blockIdx.x;
    int t; const float* feat; const int* sn; const int* rc; const float* hx; int nE;
    if (b < nb0)            { t = 0; feat = feat0; sn = s0; rc = r0; hx = hx0; nE = n0; }
    else if (b < nb0 + nb1) { t = 1; b -= nb0; feat = feat1; sn = s1; rc = r1; hx = hx1; nE = n1; }
    else                    { t = 2; b -= nb0 + nb1; feat = feat2; sn = s2; rc = r2; hx = hxn; nE = n2; }

    int tid = threadIdx.x;
    int w = tid >> 6, lane = tid & 63, lg = lane >> 4, cr = lane & 15;
    int ebase = b * EPB + w * 128;
    if (ebase >= nE) return;                    // fully-empty wave (no barriers used)
    bool partial = (ebase + 128 > nE);          // never true for this problem's sizes
    int t_off = (t == 0) ? 0 : (t == 1 ? n0 : n0 + n1);
    float* zt = z + t * (N_ELx * TPSx);

    // weight fragments + biases (L1-hot broadcast loads), amortized over 128 edges
    bf16x8 uf[4];
    #pragma unroll
    for (int tr = 0; tr < 4; ++tr)
        uf[tr] = *(const bf16x8*)(ufragT + ((t * 4 + tr) * 64 + lane) * 8);
    bf16x8 wf[4][2];
    #pragma unroll
    for (int tn = 0; tn < 4; ++tn)
        #pragma unroll
        for (int ks = 0; ks < 2; ++ks)
            wf[tn][ks] = *(const bf16x8*)(wWfrag + (((t * 2 + ks) * 4 + tn) * 64 + lane) * 8);
    float4 ubv[4];
    #pragma unroll
    for (int tr = 0; tr < 4; ++tr)
        ubv[tr] = *(const float4*)(u_b + t * 64 + tr * 16 + lg * 4);
    float wbv[4];
    #pragma unroll
    for (int tn = 0; tn < 4; ++tn)
        wbv[tn] = w_b[t * 64 + tn * 16 + cr];

    // own-edge meta (explicit scalars — rule #20)
    int pe_own0, pe_own1, s_own0, s_own1, r_own0, r_own1;
    {
        int e0i = ebase + lane;
        int e1i = ebase + 64 + lane;
        pe_own0 = perm[t_off + min(e0i, nE - 1)];
        pe_own1 = perm[t_off + min(e1i, nE - 1)];
        s_own0 = sn[pe_own0]; r_own0 = rc[pe_own0];
        s_own1 = sn[pe_own1]; r_own1 = rc[pe_own1];
    }

    const int srcA = ((lg & 1) * 2) * 16 + cr;
    const int srcB = srcA + 16;
    const bool selLow = (lg < 2);
    f32x4 zero4 = {0.f, 0.f, 0.f, 0.f};

    // deferred segment accumulator: per-lane partials, flushed on receiver change
    float accv[4] = {0.f, 0.f, 0.f, 0.f};
    int curR = -1;
    auto flush = [&]() {
        if (curR >= 0) {
            #pragma unroll
            for (int tn = 0; tn < 4; ++tn) {
                float v = accv[tn];
                v += __shfl_xor(v, 16, 64);
                v += __shfl_xor(v, 32, 64);
                if (lg == 0) atomicAdd(&zt[curR * 64 + tn * 16 + cr], v);
                accv[tn] = 0.f;
            }
        }
    };

    // ---- prologue: prefetch feat for tile 0 ----
    int pF_n = __shfl(pe_own0, cr, 64);
    float4 fa_n, fc_n;
    {
        const float4* fp = (const float4*)(feat + (size_t)pF_n * EDGE_INx + lg * 8);
        fa_n = fp[0]; fc_n = fp[1];
    }

    #pragma unroll 2
    for (int tc = 0; tc < 8; ++tc) {
        int slot_hi = (tc & 4);                  // wave-uniform
        int b16 = (tc & 3) * 16;
        float4 fa = fa_n, fc = fc_n;

        // ---- prefetch feat for tile tc+1 (issue-early, consume next iter) ----
        if (tc < 7) {
            int ntc = tc + 1;
            int npe = ((ntc & 4)) ? pe_own1 : pe_own0;
            pF_n = __shfl(npe, ((ntc & 3) * 16) + cr, 64);
            const float4* fp = (const float4*)(feat + (size_t)pF_n * EDGE_INx + lg * 8);
            fa_n = fp[0]; fc_n = fp[1];
        }

        // ---- per-tile meta via shfl; issue hx gathers early ----
        int s_cur = slot_hi ? s_own1 : s_own0;
        int r_cur = slot_hi ? r_own1 : r_own0;
        int sidv[4];
        #pragma unroll
        for (int r = 0; r < 4; ++r)
            sidv[r] = __shfl(s_cur, b16 + lg * 4 + r, 64);
        int rF = __shfl(r_cur, b16, 64);
        int rL = __shfl(r_cur, b16 + 15, 64);

        float hv[4][4];   // [tn][r] — loads issued here, consumed after GEMM2
        if (!partial) {
            #pragma unroll
            for (int r = 0; r < 4; ++r) {
                const float* hp = hx + sidv[r] * TPSx + cr;
                #pragma unroll
                for (int tn = 0; tn < 4; ++tn)
                    hv[tn][r] = hp[tn * 16];
            }
        } else {
            #pragma unroll
            for (int r = 0; r < 4; ++r) {
                bool aE = (ebase + tc * 16 + lg * 4 + r) < nE;
                const float* hp = hx + sidv[r] * TPSx + cr;
                #pragma unroll
                for (int tn = 0; tn < 4; ++tn)
                    hv[tn][r] = aE ? hp[tn * 16] : 0.f;
            }
        }

        // ---- feat B-frag from prefetched regs: feat[edge=cr][featcol=lg*8+j] ----
        bf16x8 fB = mk8(cvtpk(fa.x, fa.y), cvtpk(fa.z, fa.w),
                        cvtpk(fc.x, fc.y), cvtpk(fc.z, fc.w));

        // ---- GEMM1: e^T tiles ----
        f32x4 d1[4];
        #pragma unroll
        for (int tr = 0; tr < 4; ++tr)
            d1[tr] = __builtin_amdgcn_mfma_f32_16x16x32_bf16(uf[tr], fB, zero4, 0, 0, 0);

        // ---- silu + pack pairs (cvt_pk: 1 inst per pair) ----
        uint32_t pk1[4][2];
        #pragma unroll
        for (int tr = 0; tr < 4; ++tr) {
            float v0 = silu_f(d1[tr][0] + ubv[tr].x);
            float v1 = silu_f(d1[tr][1] + ubv[tr].y);
            float v2 = silu_f(d1[tr][2] + ubv[tr].z);
            float v3 = silu_f(d1[tr][3] + ubv[tr].w);
            pk1[tr][0] = cvtpk(v0, v1);
            pk1[tr][1] = cvtpk(v2, v3);
        }

        // ---- redistribute -> A-frag of e: lane needs e[edge=cr][ucol=32ks+8lg+j] ----
        bf16x8 ebf[2];
        #pragma unroll
        for (int ks = 0; ks < 2; ++ks) {
            int t0 = 2 * ks, t1 = 2 * ks + 1;
            uint32_t a0 = (uint32_t)__shfl((int)pk1[t0][0], srcA, 64);
            uint32_t b0 = (uint32_t)__shfl((int)pk1[t1][0], srcA, 64);
            uint32_t a1 = (uint32_t)__shfl((int)pk1[t0][1], srcA, 64);
            uint32_t b1 = (uint32_t)__shfl((int)pk1[t1][1], srcA, 64);
            uint32_t a2 = (uint32_t)__shfl((int)pk1[t0][0], srcB, 64);
            uint32_t b2 = (uint32_t)__shfl((int)pk1[t1][0], srcB, 64);
            uint32_t a3 = (uint32_t)__shfl((int)pk1[t0][1], srcB, 64);
            uint32_t b3 = (uint32_t)__shfl((int)pk1[t1][1], srcB, 64);
            ebf[ks] = mk8(selLow ? a0 : b0, selLow ? a1 : b1,
                          selLow ? a2 : b2, selLow ? a3 : b3);
        }

        // ---- GEMM2: we tiles ----
        f32x4 d2[4];
        #pragma unroll
        for (int tn = 0; tn < 4; ++tn) {
            f32x4 acc = __builtin_amdgcn_mfma_f32_16x16x32_bf16(ebf[0], wf[tn][0], zero4, 0, 0, 0);
            d2[tn] = __builtin_amdgcn_mfma_f32_16x16x32_bf16(ebf[1], wf[tn][1], acc, 0, 0, 0);
        }

        // ---- message values ----
        float m[4][4];   // [tn][r]
        #pragma unroll
        for (int tn = 0; tn < 4; ++tn)
            #pragma unroll
            for (int r = 0; r < 4; ++r)
                m[tn][r] = silu_f(d2[tn][r] + wbv[tn]) * hv[tn][r];

        // ---- segment handling: accumulate in regs, flush on receiver change ----
        if (rF == rL) {
            if (rF != curR) { flush(); curR = rF; }
            #pragma unroll
            for (int tn = 0; tn < 4; ++tn)
                accv[tn] += (m[tn][0] + m[tn][1]) + (m[tn][2] + m[tn][3]);
        } else {
            flush();
            curR = -1;
            int ridv[4];
            #pragma unroll
            for (int r = 0; r < 4; ++r)
                ridv[r] = __shfl(r_cur, b16 + lg * 4 + r, 64);
            float a0 = m[0][0], a1 = m[1][0], a2 = m[2][0], a3 = m[3][0];
            int segR = ridv[0];
            #pragma unroll
            for (int r = 1; r < 4; ++r) {
                if (ridv[r] != segR) {
                    atomicAdd(&zt[segR * 64 +  0 + cr], a0);
                    atomicAdd(&zt[segR * 64 + 16 + cr], a1);
                    atomicAdd(&zt[segR * 64 + 32 + cr], a2);
                    atomicAdd(&zt[segR * 64 + 48 + cr], a3);
                    a0 = m[0][r]; a1 = m[1][r]; a2 = m[2][r]; a3 = m[3][r];
                    segR = ridv[r];
                } else {
                    a0 += m[0][r]; a1 += m[1][r]; a2 += m[2][r]; a3 += m[3][r];
                }
            }
            atomicAdd(&zt[segR * 64 +  0 + cr], a0);
            atomicAdd(&zt[segR * 64 + 16 + cr], a1);
            atomicAdd(&zt[segR * 64 + 32 + cr], a2);
            atomicAdd(&zt[segR * 64 + 48 + cr], a3);
        }
    }
    flush();
}

// ---------------- final kernel: g-subnets + residual ----------------
__global__ __launch_bounds__(128)
void final_kernel(const float* __restrict__ elec, const float* __restrict__ z,
                  const float* __restrict__ gWres, const float* __restrict__ gbres,
                  const float* __restrict__ gWz, const float* __restrict__ gbz,
                  float* __restrict__ out)
{
    __shared__ float xe[4 * 128];
    __shared__ float xz[3 * 4 * 64];
    int b = blockIdx.x;
    int tid = threadIdx.x;
    int row0 = b * 4;
    for (int i = tid; i < 4 * 128; i += 128)
        xe[i] = elec[row0 * 128 + i];
    for (int i = tid; i < 3 * 4 * 64; i += 128) {
        int t = i >> 8; int rr = (i >> 6) & 3; int k = i & 63;
        xz[i] = z[t * N_ELx * 64 + (row0 + rr) * 64 + k];
    }
    __syncthreads();

    int col = tid;
    float accr[4] = {0.f, 0.f, 0.f, 0.f};
    for (int k = 0; k < 128; ++k) {
        float wv = gWres[k * 128 + col];
        #pragma unroll
        for (int r = 0; r < 4; ++r) accr[r] += xe[r * 128 + k] * wv;
    }
    float o[4];
    float br = gbres[col];
    #pragma unroll
    for (int r = 0; r < 4; ++r) o[r] = silu_f(accr[r] + br) + xe[r * 128 + col];

    for (int t = 0; t < 3; ++t) {
        float accz[4] = {0.f, 0.f, 0.f, 0.f};
        for (int k = 0; k < 64; ++k) {
            float wv = gWz[(t * 64 + k) * 128 + col];
            #pragma unroll
            for (int r = 0; r < 4; ++r) accz[r] += xz[t * 256 + r * 64 + k] * wv;
        }
        float bz = gbz[t * 128 + col];
        #pragma unroll
        for (int r = 0; r < 4; ++r) o[r] += silu_f(accz[r] + bz);
    }
    #pragma unroll
    for (int r = 0; r < 4; ++r) out[(row0 + r) * 128 + col] = o[r];
}

extern "C" void kernel_launch(void* const* d_in, const int* in_sizes, int n_in,
                              void* d_out, int out_size, void* d_ws, size_t ws_size,
                              hipStream_t stream)
{
    const float* elec   = (const float*)d_in[0];
    const float* nuclei = (const float*)d_in[1];
    const float* feat0  = (const float*)d_in[2];
    const float* feat1  = (const float*)d_in[3];
    const float* feat2  = (const float*)d_in[4];
    const int*   s0     = (const int*)d_in[5];
    const int*   r0     = (const int*)d_in[6];
    const int*   s1     = (const int*)d_in[7];
    const int*   r1     = (const int*)d_in[8];
    const int*   s2     = (const int*)d_in[9];
    const int*   r2     = (const int*)d_in[10];
    const float* u_W    = (const float*)d_in[11];
    const float* u_b    = (const float*)d_in[12];
    const float* w_W    = (const float*)d_in[13];
    const float* w_b    = (const float*)d_in[14];
    const float* hWee   = (const float*)d_in[15];
    const float* hbee   = (const float*)d_in[16];
    const float* hWne   = (const float*)d_in[17];
    const float* hbne   = (const float*)d_in[18];
    const float* gWres  = (const float*)d_in[19];
    const float* gbres  = (const float*)d_in[20];
    const float* gWz    = (const float*)d_in[21];
    const float* gbz    = (const float*)d_in[22];
    float* out = (float*)d_out;

    char* ws = (char*)d_ws;
    float* hx0      = (float*)(ws + 0);           // 196608
    float* hx1      = (float*)(ws + 196608);      // 196608
    float* hxn      = (float*)(ws + 393216);      // 8192
    float* z        = (float*)(ws + 401408);      // 589824
    short* ufragT   = (short*)(ws + 991232);      // 12288
    short* wWfrag   = (short*)(ws + 1003520);     // 24576
    int*   binTotal = (int*)(ws + 1028096);       // 9216
    int*   perm     = (int*)(ws + 1046528);       // 2454528
    int*   blockHist= (int*)(ws + 3501056);       // 884736  (end: 4385792)

    int n0 = in_sizes[2] / EDGE_INx;
    int n1 = in_sizes[3] / EDGE_INx;
    int n2 = in_sizes[4] / EDGE_INx;
    int nb0 = (n0 + EPB - 1) / EPB;
    int nb1 = (n1 + EPB - 1) / EPB;
    int nb2 = (n2 + EPB - 1) / EPB;

    setup_kernel<<<14 + NB_SORT, 256, 0, stream>>>(
        elec, nuclei, u_W, w_W, hWee, hbee, hWne, hbne,
        hx0, hx1, hxn, ufragT, wWfrag,
        r0, r1, r2, n0, n1, n2, blockHist, z);
    binscan_kernel<<<NBINS / 256, 256, 0, stream>>>(blockHist, binTotal);
    scatter2_kernel<<<NB_SORT, 256, 0, stream>>>(r0, r1, r2, n0, n1, n2,
                                                 blockHist, binTotal, perm);
    edge_kernel<<<nb0 + nb1 + nb2, 256, 0, stream>>>(
        feat0, feat1, feat2, s0, s1, s2, r0, r1, r2,
        u_b, w_b, hx0, hx1, hxn, ufragT, wWfrag, perm, z,
        n0, n1, n2, nb0, nb1);
    final_kernel<<<192, 128, 0, stream>>>(elec, z, gWres, gbres, gWz, gbz, out);
}

// Round 10
// 90.894 us; speedup vs baseline: 1.7135x; 1.1279x over previous
//
#include <hip/hip_runtime.h>
#include <hip/hip_bf16.h>
#include <stdint.h>

#define N_ELx 768
#define EMBx 128
#define TPSx 64
#define EDGE_INx 32
#define EPB 256            // edges per block (4 waves x 64)
#define NBINS 2304         // 3 types * 768 receivers
#define NB_SORT 96

typedef __attribute__((ext_vector_type(8))) short bf16x8;
typedef __attribute__((ext_vector_type(4))) float f32x4;
typedef __attribute__((ext_vector_type(4))) uint32_t u32x4;
typedef __attribute__((ext_vector_type(2))) uint32_t u32x2;

__device__ __forceinline__ short f2bf(float f) {
    union { float f; uint32_t u; } v; v.f = f;
    uint32_t u = v.u;
    uint32_t r = (u + 0x7FFFu + ((u >> 16) & 1u)) >> 16;
    return (short)r;
}

// 1-instruction packed f32->bf16 pair (lo -> low16, hi -> high16), RNE
__device__ __forceinline__ uint32_t cvtpk(float lo, float hi) {
    uint32_t r;
    asm("v_cvt_pk_bf16_f32 %0, %1, %2" : "=v"(r) : "v"(lo), "v"(hi));
    return r;
}

__device__ __forceinline__ bf16x8 mk8(uint32_t a, uint32_t b, uint32_t c, uint32_t d) {
    union { u32x4 u; bf16x8 h; } x;
    x.u = (u32x4){a, b, c, d};
    return x.h;
}

// fast silu: 5 VALU insts (mul, exp2, add, rcp, mul) — avoids fp32 div sequence
__device__ __forceinline__ float silu_f(float x) {
    float e = __builtin_amdgcn_exp2f(-1.442695041f * x);
    return x * __builtin_amdgcn_rcpf(1.0f + e);
}

// ---------------- setup kernel: prep (blocks 0..13) + blockhist (14..109) ----
__global__ __launch_bounds__(256)
void setup_kernel(const float* __restrict__ elec, const float* __restrict__ nuclei,
                  const float* __restrict__ uW, const float* __restrict__ wW,
                  const float* __restrict__ hWee, const float* __restrict__ hbee,
                  const float* __restrict__ hWne, const float* __restrict__ hbne,
                  float* __restrict__ hx0, float* __restrict__ hx1, float* __restrict__ hxn,
                  short* __restrict__ ufragT, short* __restrict__ wWfrag,
                  const int* __restrict__ r0, const int* __restrict__ r1,
                  const int* __restrict__ r2,
                  int n0, int n1, int n2, int* __restrict__ blockHist,
                  float* __restrict__ z)
{
    __shared__ __align__(16) char smem[32768];
    int b = blockIdx.x;
    int tid = threadIdx.x;
    if (b < 12) {
        short* lds_a = (short*)smem;   // [kk*4+kc][row][8]
        int t = b / 6, rb = b % 6;
        const float* W = hWee + t * (128 * 64);
        {
            int row = tid >> 1, half = tid & 1;
            const float4* src = (const float4*)(elec + (size_t)(rb * 128 + row) * 128 + half * 64);
            #pragma unroll
            for (int c = 0; c < 8; ++c) {
                float4 fa = src[c * 2 + 0], fb = src[c * 2 + 1];
                bf16x8 v;
                v[0] = f2bf(fa.x); v[1] = f2bf(fa.y); v[2] = f2bf(fa.z); v[3] = f2bf(fa.w);
                v[4] = f2bf(fb.x); v[5] = f2bf(fb.y); v[6] = f2bf(fb.z); v[7] = f2bf(fb.w);
                int kk = half * 2 + (c >> 2), kc = c & 3;
                *(bf16x8*)&lds_a[((kk * 4 + kc) * 128 + row) * 8] = v;
            }
        }
        __syncthreads();
        int lane = tid & 63, w = tid >> 6, kc = lane >> 4, cr = lane & 15;
        int col = w * 16 + cr;
        bf16x8 bfrag[4];
        #pragma unroll
        for (int kk = 0; kk < 4; ++kk) {
            bf16x8 v;
            #pragma unroll
            for (int j = 0; j < 8; ++j)
                v[j] = f2bf(W[(kk * 32 + kc * 8 + j) * 64 + col]);
            bfrag[kk] = v;
        }
        float bias = hbee[t * 64 + col];
        float* dst = (t == 0 ? hx0 : hx1);
        f32x4 zero4 = {0.f, 0.f, 0.f, 0.f};
        #pragma unroll
        for (int rt = 0; rt < 8; ++rt) {
            f32x4 acc = zero4;
            #pragma unroll
            for (int kk = 0; kk < 4; ++kk) {
                bf16x8 a = *(const bf16x8*)&lds_a[((kk * 4 + kc) * 128 + rt * 16 + cr) * 8];
                acc = __builtin_amdgcn_mfma_f32_16x16x32_bf16(a, bfrag[kk], acc, 0, 0, 0);
            }
            #pragma unroll
            for (int r = 0; r < 4; ++r) {
                int row = rb * 128 + rt * 16 + kc * 4 + r;
                dst[row * 64 + col] = silu_f(acc[r] + bias);
            }
        }
    } else if (b == 12) {
        // hxn: silu(nuclei @ hWne + hbne), 32x64 @ 64x64 (tiny, scalar)
        int lr = tid >> 6, col = tid & 63;
        for (int i = 0; i < 8; ++i) {
            int row = lr * 8 + i;
            float acc = 0.f;
            for (int k = 0; k < 64; ++k)
                acc += nuclei[row * 64 + k] * hWne[k * 64 + col];
            hxn[row * 64 + col] = silu_f(acc + hbne[col]);
        }
    } else if (b == 13) {
        // ufragT: A-fragment of uW^T: A[ucol=tr*16+cr][k=featcol=lg*8+j]
        for (int idx = tid; idx < 3 * 4 * 64; idx += 256) {
            int lane = idx & 63, tr = (idx >> 6) & 3, ty = idx >> 8;
            int lg = lane >> 4, cr = lane & 15;
            for (int j = 0; j < 8; ++j)
                ufragT[idx * 8 + j] =
                    f2bf(uW[(ty * EDGE_INx + lg * 8 + j) * TPSx + tr * 16 + cr]);
        }
        // wWfrag: B-fragment of wW: B[k=ks*32+lg*8+j][col=tn*16+cr]
        for (int idx = tid; idx < 3 * 2 * 4 * 64; idx += 256) {
            int lane = idx & 63, ct = (idx >> 6) & 3, ks = (idx >> 8) & 1, ty = idx >> 9;
            for (int j = 0; j < 8; ++j) {
                int k = ks * 32 + (lane >> 4) * 8 + j, col = ct * 16 + (lane & 15);
                wWfrag[idx * 8 + j] = f2bf(wW[(ty * 64 + k) * 64 + col]);
            }
        }
    } else {
        // blockhist for sort + fold-in z zeroing
        int* h = (int*)smem;
        int bb = b - 14;
        for (int i = bb * 256 + tid; i < 3 * N_ELx * TPSx; i += NB_SORT * 256)
            z[i] = 0.f;
        for (int i = tid; i < NBINS; i += 256) h[i] = 0;
        __syncthreads();
        int total = n0 + n1 + n2;
        int chunk = (total + NB_SORT - 1) / NB_SORT;
        int start = bb * chunk, end = min(start + chunk, total);
        for (int i = start + tid; i < end; i += 256) {
            int t, j;
            if (i < n0)            { t = 0; j = i; }
            else if (i < n0 + n1)  { t = 1; j = i - n0; }
            else                   { t = 2; j = i - n0 - n1; }
            int rv = (t == 0 ? r0 : (t == 1 ? r1 : r2))[j];
            atomicAdd(&h[t * 768 + rv], 1);
        }
        __syncthreads();
        for (int i = tid; i < NBINS; i += 256)
            blockHist[i * NB_SORT + bb] = h[i];
    }
}

// ---------------- sort: wave-per-bin parallel scan, then scatter -------------
__global__ __launch_bounds__(256)
void binscan_kernel(int* __restrict__ blockHist, int* __restrict__ binTotal)
{
    int tid = threadIdx.x;
    int w = tid >> 6, lane = tid & 63;
    int bin = blockIdx.x * 4 + w;            // grid = NBINS/4 = 576
    int* p = blockHist + bin * NB_SORT;      // 96 entries
    int a = p[lane];
    int bv = (lane < 32) ? p[64 + lane] : 0;
    int a0 = a, b0 = bv;
    // inclusive scan of a over 64 lanes
    #pragma unroll
    for (int d = 1; d < 64; d <<= 1) {
        int tv = __shfl_up(a, d, 64);
        if (lane >= d) a += tv;
    }
    int sumA = __shfl(a, 63, 64);
    // inclusive scan of bv over lanes 0..31
    #pragma unroll
    for (int d = 1; d < 32; d <<= 1) {
        int tv = __shfl_up(bv, d, 64);
        if (lane >= d) bv += tv;
    }
    p[lane] = a - a0;                        // exclusive
    if (lane < 32) p[64 + lane] = sumA + bv - b0;
    if (lane == 31) binTotal[bin] = sumA + bv;
}

__global__ __launch_bounds__(256)
void scatter2_kernel(const int* __restrict__ r0, const int* __restrict__ r1,
                     const int* __restrict__ r2,
                     int n0, int n1, int n2,
                     const int* __restrict__ blockHist,
                     const int* __restrict__ binTotal,
                     int* __restrict__ perm)
{
    __shared__ int cursor[NBINS];
    __shared__ int part[256];
    int tid = threadIdx.x, b = blockIdx.x;
    // per-block redundant exclusive scan of binTotal
    int l[9]; int s = 0;
    #pragma unroll
    for (int j = 0; j < 9; ++j) { l[j] = binTotal[tid * 9 + j]; s += l[j]; }
    part[tid] = s;
    __syncthreads();
    for (int off = 1; off < 256; off <<= 1) {
        int v = (tid >= off) ? part[tid - off] : 0;
        __syncthreads();
        part[tid] += v;
        __syncthreads();
    }
    int run = (tid == 0) ? 0 : part[tid - 1];
    #pragma unroll
    for (int j = 0; j < 9; ++j) {
        int bin = tid * 9 + j;
        cursor[bin] = run + blockHist[bin * NB_SORT + b];
        run += l[j];
    }
    __syncthreads();
    int total = n0 + n1 + n2;
    int chunk = (total + NB_SORT - 1) / NB_SORT;
    int start = b * chunk, end = min(start + chunk, total);
    for (int i = start + tid; i < end; i += 256) {
        int t, j;
        if (i < n0)            { t = 0; j = i; }
        else if (i < n0 + n1)  { t = 1; j = i - n0; }
        else                   { t = 2; j = i - n0 - n1; }
        int rv = (t == 0 ? r0 : (t == 1 ? r1 : r2))[j];
        int pos = atomicAdd(&cursor[t * 768 + rv], 1);
        perm[pos] = j;
    }
}

// ---------------- edge kernel: 64 edges/wave, per-wave LDS transpose ---------
// GEMM1 (swapped): e^T = mfma(A = uW^T frag, B = feat^T from global, prefetched)
// e^T -> cvtpk -> per-wave LDS buffer (row=edge, 144B stride) -> ds_read_b128
//   A-frags of e (no barrier needed: same-wave DS ordering)
// GEMM2 (normal): we = mfma(A = e frag, B = wWfrag)  (edges register-local)
// epilogue: silu * hx[sender]; per-lane acc across tiles, flush on receiver change
__global__ __launch_bounds__(256)
void edge_kernel(const float* __restrict__ feat0, const float* __restrict__ feat1,
                 const float* __restrict__ feat2,
                 const int* __restrict__ s0, const int* __restrict__ s1, const int* __restrict__ s2,
                 const int* __restrict__ r0, const int* __restrict__ r1, const int* __restrict__ r2,
                 const float* __restrict__ u_b, const float* __restrict__ w_b,
                 const float* __restrict__ hx0, const float* __restrict__ hx1,
                 const float* __restrict__ hxn,
                 const short* __restrict__ ufragT, const short* __restrict__ wWfrag,
                 const int* __restrict__ perm,
                 float* __restrict__ z,
                 int n0, int n1, int n2, int nb0, int nb1)
{
    __shared__ __align__(16) char ebuf_all[4][16 * 144];   // 2304B per wave

    int b = blockIdx.x;
    int t; const float* feat; const int* sn; const int* rc; const float* hx; int nE;
    if (b < nb0)            { t = 0; feat = feat0; sn = s0; rc = r0; hx = hx0; nE = n0; }
    else if (b < nb0 + nb1) { t = 1; b -= nb0; feat = feat1; sn = s1; rc = r1; hx = hx1; nE = n1; }
    else                    { t = 2; b -= nb0 + nb1; feat = feat2; sn = s2; rc = r2; hx = hxn; nE = n2; }

    int tid = threadIdx.x;
    int w = tid >> 6, lane = tid & 63, lg = lane >> 4, cr = lane & 15;
    int ebase = b * EPB + w * 64;
    if (ebase >= nE) return;                    // fully-empty wave (no barriers used)
    bool partial = (ebase + 64 > nE);           // never true: all counts divide 256
    char* ebuf = ebuf_all[w];
    int t_off = (t == 0) ? 0 : (t == 1 ? n0 : n0 + n1);
    float* zt = z + t * (N_ELx * TPSx);

    // weight fragments + biases (L2-hot broadcast loads)
    bf16x8 uf[4];
    #pragma unroll
    for (int tr = 0; tr < 4; ++tr)
        uf[tr] = *(const bf16x8*)(ufragT + ((t * 4 + tr) * 64 + lane) * 8);
    bf16x8 wf[4][2];
    #pragma unroll
    for (int tn = 0; tn < 4; ++tn)
        #pragma unroll
        for (int ks = 0; ks < 2; ++ks)
            wf[tn][ks] = *(const bf16x8*)(wWfrag + (((t * 2 + ks) * 4 + tn) * 64 + lane) * 8);
    float4 ubv[4];
    #pragma unroll
    for (int tr = 0; tr < 4; ++tr)
        ubv[tr] = *(const float4*)(u_b + t * 64 + tr * 16 + lg * 4);
    float wbv[4];
    #pragma unroll
    for (int tn = 0; tn < 4; ++tn)
        wbv[tn] = w_b[t * 64 + tn * 16 + cr];

    // own-edge meta: lane owns edge ebase + lane
    int e_own = ebase + lane;
    int pe_own = perm[t_off + min(e_own, nE - 1)];
    int s_own = sn[pe_own];
    int r_own = rc[pe_own];

    f32x4 zero4 = {0.f, 0.f, 0.f, 0.f};

    // deferred segment accumulator: per-lane partials, flushed on receiver change
    float accv[4] = {0.f, 0.f, 0.f, 0.f};
    int curR = -1;
    auto flush = [&]() {
        if (curR >= 0) {
            #pragma unroll
            for (int tn = 0; tn < 4; ++tn) {
                float v = accv[tn];
                v += __shfl_xor(v, 16, 64);
                v += __shfl_xor(v, 32, 64);
                if (lg == 0) atomicAdd(&zt[curR * 64 + tn * 16 + cr], v);
                accv[tn] = 0.f;
            }
        }
    };

    // ---- prologue: prefetch feat for tile 0 ----
    int pF_n = __shfl(pe_own, cr, 64);
    float4 fa_n, fc_n;
    {
        const float4* fp = (const float4*)(feat + (size_t)pF_n * EDGE_INx + lg * 8);
        fa_n = fp[0]; fc_n = fp[1];
    }

    #pragma unroll 2
    for (int tc = 0; tc < 4; ++tc) {
        int b16 = tc * 16;
        float4 fa = fa_n, fc = fc_n;

        // ---- prefetch feat for tile tc+1 (issue-early, consume next iter) ----
        if (tc < 3) {
            pF_n = __shfl(pe_own, (tc + 1) * 16 + cr, 64);
            const float4* fp = (const float4*)(feat + (size_t)pF_n * EDGE_INx + lg * 8);
            fa_n = fp[0]; fc_n = fp[1];
        }

        // ---- per-tile meta via shfl; issue hx gathers early ----
        int sidv[4];
        #pragma unroll
        for (int r = 0; r < 4; ++r)
            sidv[r] = __shfl(s_own, b16 + lg * 4 + r, 64);
        int rF = __shfl(r_own, b16, 64);
        int rL = __shfl(r_own, b16 + 15, 64);

        float hv[4][4];   // [tn][r] — loads issued here, consumed after GEMM2
        if (!partial) {
            #pragma unroll
            for (int r = 0; r < 4; ++r) {
                const float* hp = hx + sidv[r] * TPSx + cr;
                #pragma unroll
                for (int tn = 0; tn < 4; ++tn)
                    hv[tn][r] = hp[tn * 16];
            }
        } else {
            #pragma unroll
            for (int r = 0; r < 4; ++r) {
                bool aE = (ebase + b16 + lg * 4 + r) < nE;
                const float* hp = hx + sidv[r] * TPSx + cr;
                #pragma unroll
                for (int tn = 0; tn < 4; ++tn)
                    hv[tn][r] = aE ? hp[tn * 16] : 0.f;
            }
        }

        // ---- feat B-frag from prefetched regs: feat[edge=cr][featcol=lg*8+j] ----
        bf16x8 fB = mk8(cvtpk(fa.x, fa.y), cvtpk(fa.z, fa.w),
                        cvtpk(fc.x, fc.y), cvtpk(fc.z, fc.w));

        // ---- GEMM1: e^T tiles ----
        f32x4 d1[4];
        #pragma unroll
        for (int tr = 0; tr < 4; ++tr)
            d1[tr] = __builtin_amdgcn_mfma_f32_16x16x32_bf16(uf[tr], fB, zero4, 0, 0, 0);

        // ---- silu + pack + per-wave LDS transpose write ----
        // lane holds e^T[ucol=tr*16+lg*4+{0..3}][edge=cr] -> write at
        // ebuf[cr*144 + ucol*2] (row=edge, ascending ucol, 144B stride)
        #pragma unroll
        for (int tr = 0; tr < 4; ++tr) {
            float v0 = silu_f(d1[tr][0] + ubv[tr].x);
            float v1 = silu_f(d1[tr][1] + ubv[tr].y);
            float v2 = silu_f(d1[tr][2] + ubv[tr].z);
            float v3 = silu_f(d1[tr][3] + ubv[tr].w);
            u32x2 pk; pk[0] = cvtpk(v0, v1); pk[1] = cvtpk(v2, v3);
            *(u32x2*)(ebuf + cr * 144 + tr * 32 + lg * 8) = pk;
        }

        // ---- read A-frags of e: lane needs e[edge=cr][ucol=ks*32+lg*8+j] ----
        // same-wave DS ordering: no barrier needed
        bf16x8 ebf0 = *(const bf16x8*)(ebuf + cr * 144 + 0 * 64 + lg * 16);
        bf16x8 ebf1 = *(const bf16x8*)(ebuf + cr * 144 + 1 * 64 + lg * 16);

        // ---- GEMM2: we tiles ----
        f32x4 d2[4];
        #pragma unroll
        for (int tn = 0; tn < 4; ++tn) {
            f32x4 acc = __builtin_amdgcn_mfma_f32_16x16x32_bf16(ebf0, wf[tn][0], zero4, 0, 0, 0);
            d2[tn] = __builtin_amdgcn_mfma_f32_16x16x32_bf16(ebf1, wf[tn][1], acc, 0, 0, 0);
        }

        // ---- message values ----
        float m[4][4];   // [tn][r]
        #pragma unroll
        for (int tn = 0; tn < 4; ++tn)
            #pragma unroll
            for (int r = 0; r < 4; ++r)
                m[tn][r] = silu_f(d2[tn][r] + wbv[tn]) * hv[tn][r];

        // ---- segment handling: accumulate in regs, flush on receiver change ----
        if (rF == rL) {
            if (rF != curR) { flush(); curR = rF; }
            #pragma unroll
            for (int tn = 0; tn < 4; ++tn)
                accv[tn] += (m[tn][0] + m[tn][1]) + (m[tn][2] + m[tn][3]);
        } else {
            flush();
            curR = -1;
            int ridv[4];
            #pragma unroll
            for (int r = 0; r < 4; ++r)
                ridv[r] = __shfl(r_own, b16 + lg * 4 + r, 64);
            float a0 = m[0][0], a1 = m[1][0], a2 = m[2][0], a3 = m[3][0];
            int segR = ridv[0];
            #pragma unroll
            for (int r = 1; r < 4; ++r) {
                if (ridv[r] != segR) {
                    atomicAdd(&zt[segR * 64 +  0 + cr], a0);
                    atomicAdd(&zt[segR * 64 + 16 + cr], a1);
                    atomicAdd(&zt[segR * 64 + 32 + cr], a2);
                    atomicAdd(&zt[segR * 64 + 48 + cr], a3);
                    a0 = m[0][r]; a1 = m[1][r]; a2 = m[2][r]; a3 = m[3][r];
                    segR = ridv[r];
                } else {
                    a0 += m[0][r]; a1 += m[1][r]; a2 += m[2][r]; a3 += m[3][r];
                }
            }
            atomicAdd(&zt[segR * 64 +  0 + cr], a0);
            atomicAdd(&zt[segR * 64 + 16 + cr], a1);
            atomicAdd(&zt[segR * 64 + 32 + cr], a2);
            atomicAdd(&zt[segR * 64 + 48 + cr], a3);
        }
    }
    flush();
}

// ---------------- final kernel: g-subnets + residual ----------------
__global__ __launch_bounds__(128)
void final_kernel(const float* __restrict__ elec, const float* __restrict__ z,
                  const float* __restrict__ gWres, const float* __restrict__ gbres,
                  const float* __restrict__ gWz, const float* __restrict__ gbz,
                  float* __restrict__ out)
{
    __shared__ float xe[4 * 128];
    __shared__ float xz[3 * 4 * 64];
    int b = blockIdx.x;
    int tid = threadIdx.x;
    int row0 = b * 4;
    for (int i = tid; i < 4 * 128; i += 128)
        xe[i] = elec[row0 * 128 + i];
    for (int i = tid; i < 3 * 4 * 64; i += 128) {
        int t = i >> 8; int rr = (i >> 6) & 3; int k = i & 63;
        xz[i] = z[t * N_ELx * 64 + (row0 + rr) * 64 + k];
    }
    __syncthreads();

    int col = tid;
    float accr[4] = {0.f, 0.f, 0.f, 0.f};
    for (int k = 0; k < 128; ++k) {
        float wv = gWres[k * 128 + col];
        #pragma unroll
        for (int r = 0; r < 4; ++r) accr[r] += xe[r * 128 + k] * wv;
    }
    float o[4];
    float br = gbres[col];
    #pragma unroll
    for (int r = 0; r < 4; ++r) o[r] = silu_f(accr[r] + br) + xe[r * 128 + col];

    for (int t = 0; t < 3; ++t) {
        float accz[4] = {0.f, 0.f, 0.f, 0.f};
        for (int k = 0; k < 64; ++k) {
            float wv = gWz[(t * 64 + k) * 128 + col];
            #pragma unroll
            for (int r = 0; r < 4; ++r) accz[r] += xz[t * 256 + r * 64 + k] * wv;
        }
        float bz = gbz[t * 128 + col];
        #pragma unroll
        for (int r = 0; r < 4; ++r) o[r] += silu_f(accz[r] + bz);
    }
    #pragma unroll
    for (int r = 0; r < 4; ++r) out[(row0 + r) * 128 + col] = o[r];
}

extern "C" void kernel_launch(void* const* d_in, const int* in_sizes, int n_in,
                              void* d_out, int out_size, void* d_ws, size_t ws_size,
                              hipStream_t stream)
{
    const float* elec   = (const float*)d_in[0];
    const float* nuclei = (const float*)d_in[1];
    const float* feat0  = (const float*)d_in[2];
    const float* feat1  = (const float*)d_in[3];
    const float* feat2  = (const float*)d_in[4];
    const int*   s0     = (const int*)d_in[5];
    const int*   r0     = (const int*)d_in[6];
    const int*   s1     = (const int*)d_in[7];
    const int*   r1     = (const int*)d_in[8];
    const int*   s2     = (const int*)d_in[9];
    const int*   r2     = (const int*)d_in[10];
    const float* u_W    = (const float*)d_in[11];
    const float* u_b    = (const float*)d_in[12];
    const float* w_W    = (const float*)d_in[13];
    const float* w_b    = (const float*)d_in[14];
    const float* hWee   = (const float*)d_in[15];
    const float* hbee   = (const float*)d_in[16];
    const float* hWne   = (const float*)d_in[17];
    const float* hbne   = (const float*)d_in[18];
    const float* gWres  = (const float*)d_in[19];
    const float* gbres  = (const float*)d_in[20];
    const float* gWz    = (const float*)d_in[21];
    const float* gbz    = (const float*)d_in[22];
    float* out = (float*)d_out;

    char* ws = (char*)d_ws;
    float* hx0      = (float*)(ws + 0);           // 196608
    float* hx1      = (float*)(ws + 196608);      // 196608
    float* hxn      = (float*)(ws + 393216);      // 8192
    float* z        = (float*)(ws + 401408);      // 589824
    short* ufragT   = (short*)(ws + 991232);      // 12288
    short* wWfrag   = (short*)(ws + 1003520);     // 24576
    int*   binTotal = (int*)(ws + 1028096);       // 9216
    int*   perm     = (int*)(ws + 1046528);       // 2454528
    int*   blockHist= (int*)(ws + 3501056);       // 884736  (end: 4385792)

    int n0 = in_sizes[2] / EDGE_INx;
    int n1 = in_sizes[3] / EDGE_INx;
    int n2 = in_sizes[4] / EDGE_INx;
    int nb0 = (n0 + EPB - 1) / EPB;
    int nb1 = (n1 + EPB - 1) / EPB;
    int nb2 = (n2 + EPB - 1) / EPB;

    setup_kernel<<<14 + NB_SORT, 256, 0, stream>>>(
        elec, nuclei, u_W, w_W, hWee, hbee, hWne, hbne,
        hx0, hx1, hxn, ufragT, wWfrag,
        r0, r1, r2, n0, n1, n2, blockHist, z);
    binscan_kernel<<<NBINS / 4, 256, 0, stream>>>(blockHist, binTotal);
    scatter2_kernel<<<NB_SORT, 256, 0, stream>>>(r0, r1, r2, n0, n1, n2,
                                                 blockHist, binTotal, perm);
    edge_kernel<<<nb0 + nb1 + nb2, 256, 0, stream>>>(
        feat0, feat1, feat2, s0, s1, s2, r0, r1, r2,
        u_b, w_b, hx0, hx1, hxn, ufragT, wWfrag, perm, z,
        n0, n1, n2, nb0, nb1);
    final_kernel<<<192, 128, 0, stream>>>(elec, z, gWres, gbres, gWz, gbz, out);
}